// Round 15
// baseline (114.248 us; speedup 1.0000x reference)
//
#include <hip/hip_runtime.h>
#include <hip/hip_fp16.h>

// Seesaw_Conv: 3x3 conv (16->128) offsets -> scrambled bilinear sampling -> 9-tap weighted sum + residual
// B=4, C=16, H=W=192, K=3, KE=9, M=4
// ws layout: [0,73728): Wpack (f16 hi/lo B-fragments); [73728,+75497472): off2 float2[64][4][192][192]
// Conv: MFMA implicit GEMM, 128 couts/block (R7 geometry + R13 prefetch + LB(256,2) so no spill).
// Sampler V2 (R14, validated): coalesced offset reads, swizzled pbuf regroup, full-unroll taps.

#define HH 192
#define WW 192
#define CC 16
#define CO 128
#define IMG_N (HH * WW)
#define ISTR 194  // img LDS row stride in halves (97 dwords, odd -> bank-clean)
#define XSTR 10   // dwords per (row,col) cell in conv packed x-tile

typedef _Float16 f16x8 __attribute__((ext_vector_type(8)));
typedef float f32x4 __attribute__((ext_vector_type(4)));
typedef uint u32x4 __attribute__((ext_vector_type(4)));

static __device__ __forceinline__ f16x8 ld_frag_global(const uint* p) {
  u32x4 v = *(const u32x4*)p;
  return __builtin_bit_cast(f16x8, v);
}

// Prepack W into MFMA B-fragment order, f16 hi+lo. (validated)
__global__ __launch_bounds__(256) void prepack_w_kernel(
    const float* __restrict__ Wref, uint* __restrict__ Wpack) {
  int e = blockIdx.x * 256 + threadIdx.x;
  if (e >= 2304) return;
  int s, btg, l;
  if (e < 2048) { s = e >> 9; int rem = e & 511; btg = rem >> 6; l = rem & 63; }
  else { s = 4; int rem = e - 2048; btg = rem >> 5; l = rem & 31; }
  int g = l >> 4;
  int tap = s * 2 + (g >> 1);
  int co = btg * 16 + (l & 15);
  int cin0 = (g & 1) * 8;
  int kh = (tap * 11) >> 5;
  int kw = tap - 3 * kh;
  uint hd[4], ld[4];
  #pragma unroll
  for (int j = 0; j < 4; ++j) {
    uint hh[2], ll[2];
    #pragma unroll
    for (int q = 0; q < 2; ++q) {
      int i = 2 * j + q;
      float v = Wref[((co * CC + cin0 + i) * 3 + kh) * 3 + kw];
      __half h = __float2half(v);
      __half lo = __float2half(v - __half2float(h));
      hh[q] = __half_as_ushort(h);
      ll[q] = __half_as_ushort(lo);
    }
    hd[j] = hh[0] | (hh[1] << 16);
    ld[j] = ll[0] | (ll[1] << 16);
  }
  uint base = (e < 2048) ? (uint)e * 8u : 16384u + (uint)(btg * 32 + l) * 8u;
  #pragma unroll
  for (int j = 0; j < 4; ++j) { Wpack[base + j] = hd[j]; Wpack[base + 4 + j] = ld[j]; }
}

struct WF { f16x8 bh0, bl0, bh1, bl1; };

static __device__ __forceinline__ WF load_w(const uint* __restrict__ Wpack,
                                            int s, int btg0, int l) {
  WF f;
  u32x4 z4 = {0, 0, 0, 0};
  f.bh0 = __builtin_bit_cast(f16x8, z4);
  f.bl0 = f.bh0; f.bh1 = f.bh0; f.bl1 = f.bh0;
  if (s < 4) {
    const uint* bp0 = Wpack + (size_t)((s * 8 + btg0) * 64 + l) * 8;
    f.bh0 = ld_frag_global(bp0);
    f.bl0 = ld_frag_global(bp0 + 4);
    const uint* bp1 = Wpack + (size_t)((s * 8 + btg0 + 1) * 64 + l) * 8;
    f.bh1 = ld_frag_global(bp1);
    f.bl1 = ld_frag_global(bp1 + 4);
  } else if (l < 32) {
    const uint* bp0 = Wpack + 16384 + (size_t)(btg0 * 32 + l) * 8;
    f.bh0 = ld_frag_global(bp0);
    f.bl0 = ld_frag_global(bp0 + 4);
    const uint* bp1 = Wpack + 16384 + (size_t)((btg0 + 1) * 32 + l) * 8;
    f.bh1 = ld_frag_global(bp1);
    f.bl1 = ld_frag_global(bp1 + 4);
  }
  return f;
}

// MFMA conv. Block: 2 rows x 64 w x 128 co (R7 geometry), 256 thr = 4 waves.
// LB(256,2) -> 256-VGPR budget: acc[4][4] + 4 WF pairs fit without spill (R7's failure mode).
__global__ __launch_bounds__(256, 2) void conv_kernel(
    const float* __restrict__ x, const uint* __restrict__ Wpack,
    const float* __restrict__ bref, float2* __restrict__ off2) {
  __shared__ uint smem[2 * 2640];  // XH | XL (21120 B); epilogue reuse: float sb[128*33]
  uint* XH = smem;
  uint* XL = smem + 2640;
  int bid = blockIdx.x;
  int wt_ = bid % 3;
  int hp = (bid / 3) % 96;
  int b = bid / 288;
  int w0 = wt_ * 64, h0 = hp * 2;
  int t = threadIdx.x;
  int l = t & 63, wv = t >> 6;
  int r = wv & 1, wn = wv >> 1;
  int g = l >> 4, l15 = l & 15;
  int btgA = wn * 4;      // bt 0,1
  int btgB = wn * 4 + 2;  // bt 2,3

  WF curA = load_w(Wpack, 0, btgA, l);  // overlaps x staging
  WF curB = load_w(Wpack, 0, btgB, l);

  for (int idx = t; idx < 2112; idx += 256) {
    int cp = idx / 264;
    int rem = idx - cp * 264;
    int row = rem / 66;
    int col = rem - row * 66;
    int gh = h0 + row - 1, gw = w0 + col - 1;
    float v0 = 0.0f, v1 = 0.0f;
    if ((unsigned)gh < 192u && (unsigned)gw < 192u) {
      const float* gp = x + ((size_t)(b * CC + 2 * cp) * HH + gh) * WW + gw;
      v0 = gp[0];
      v1 = gp[IMG_N];
    }
    __half ha = __float2half(v0), hb = __float2half(v1);
    __half la = __float2half(v0 - __half2float(ha));
    __half lb = __float2half(v1 - __half2float(hb));
    int a = (row * 66 + col) * XSTR + cp;
    XH[a] = (uint)__half_as_ushort(ha) | ((uint)__half_as_ushort(hb) << 16);
    XL[a] = (uint)__half_as_ushort(la) | ((uint)__half_as_ushort(lb) << 16);
  }

  int base0 = (r * 66 + l15) * XSTR + (g & 1) * 4;
  int tapl = g >> 1;
  f32x4 acc[4][4];
  #pragma unroll
  for (int af = 0; af < 4; ++af)
    #pragma unroll
    for (int bt = 0; bt < 4; ++bt) acc[af][bt] = (f32x4){0.f, 0.f, 0.f, 0.f};

  __syncthreads();

  #pragma unroll 1
  for (int s = 0; s < 5; ++s) {
    WF nxtA = curA, nxtB = curB;
    if (s < 4) {
      nxtA = load_w(Wpack, s + 1, btgA, l);  // issue early; waits land next iter
      nxtB = load_w(Wpack, s + 1, btgB, l);
    }
    int tap = s * 2 + tapl;
    if (tap > 8) tap = 8;
    int kh = (tap * 11) >> 5;
    int kw = tap - 3 * kh;
    int delta = (kh * 66 + kw) * XSTR;
    #pragma unroll
    for (int af = 0; af < 4; ++af) {
      int ap = base0 + af * (16 * XSTR) + delta;
      uint2 h01 = *(const uint2*)&XH[ap];
      uint2 h23 = *(const uint2*)&XH[ap + 2];
      uint2 l01 = *(const uint2*)&XL[ap];
      uint2 l23 = *(const uint2*)&XL[ap + 2];
      u32x4 th = {h01.x, h01.y, h23.x, h23.y};
      u32x4 tl = {l01.x, l01.y, l23.x, l23.y};
      f16x8 ah = __builtin_bit_cast(f16x8, th);
      f16x8 al = __builtin_bit_cast(f16x8, tl);
      acc[af][0] = __builtin_amdgcn_mfma_f32_16x16x32_f16(ah, curA.bh0, acc[af][0], 0, 0, 0);
      acc[af][0] = __builtin_amdgcn_mfma_f32_16x16x32_f16(ah, curA.bl0, acc[af][0], 0, 0, 0);
      acc[af][0] = __builtin_amdgcn_mfma_f32_16x16x32_f16(al, curA.bh0, acc[af][0], 0, 0, 0);
      acc[af][1] = __builtin_amdgcn_mfma_f32_16x16x32_f16(ah, curA.bh1, acc[af][1], 0, 0, 0);
      acc[af][1] = __builtin_amdgcn_mfma_f32_16x16x32_f16(ah, curA.bl1, acc[af][1], 0, 0, 0);
      acc[af][1] = __builtin_amdgcn_mfma_f32_16x16x32_f16(al, curA.bh1, acc[af][1], 0, 0, 0);
      acc[af][2] = __builtin_amdgcn_mfma_f32_16x16x32_f16(ah, curB.bh0, acc[af][2], 0, 0, 0);
      acc[af][2] = __builtin_amdgcn_mfma_f32_16x16x32_f16(ah, curB.bl0, acc[af][2], 0, 0, 0);
      acc[af][2] = __builtin_amdgcn_mfma_f32_16x16x32_f16(al, curB.bh0, acc[af][2], 0, 0, 0);
      acc[af][3] = __builtin_amdgcn_mfma_f32_16x16x32_f16(ah, curB.bh1, acc[af][3], 0, 0, 0);
      acc[af][3] = __builtin_amdgcn_mfma_f32_16x16x32_f16(ah, curB.bl1, acc[af][3], 0, 0, 0);
      acc[af][3] = __builtin_amdgcn_mfma_f32_16x16x32_f16(al, curB.bh1, acc[af][3], 0, 0, 0);
    }
    curA = nxtA;
    curB = nxtB;
  }

  // epilogue: R7-validated pair-planar store via LDS transpose (reuses smem)
  float bias[4];
  #pragma unroll
  for (int bt = 0; bt < 4; ++bt) bias[bt] = bref[wn * 64 + bt * 16 + l15];
  float* sb = (float*)smem;
  #pragma unroll 1
  for (int c = 0; c < 4; ++c) {
    __syncthreads();
    if (wn == (c >> 1)) {
      #pragma unroll
      for (int btl = 0; btl < 2; ++btl) {
        int bt = (c & 1) * 2 + btl;
        #pragma unroll
        for (int af = 0; af < 4; ++af)
          #pragma unroll
          for (int reg = 0; reg < 4; ++reg) {
            int px = r * 64 + af * 16 + g * 4 + reg;  // C/D: row=(l>>4)*4+reg, col=l&15
            sb[px * 33 + btl * 16 + l15] = acc[af][bt][reg] + bias[bt];
          }
      }
    }
    __syncthreads();
    int p_l = t >> 4, pxg = t & 15;
    int pair = c * 16 + p_l;
    int rr = pxg >> 3;
    float2* gbase = off2 + ((size_t)(pair * 4 + b) * IMG_N) + (h0 + rr) * WW + w0 + (pxg & 7) * 8;
    #pragma unroll
    for (int e2 = 0; e2 < 4; ++e2) {
      int px = pxg * 8 + e2 * 2;
      float4 v = {sb[px * 33 + 2 * p_l], sb[px * 33 + 2 * p_l + 1],
                  sb[(px + 1) * 33 + 2 * p_l], sb[(px + 1) * 33 + 2 * p_l + 1]};
      *(float4*)(gbase + e2 * 2) = v;
    }
  }
}

// Sampler V2 plane processor (R14, validated). Full-unroll taps for ILP.
template <int MODE>  // 0 = normal (ke2<4), 1 = sym (ke2>4), 2 = center (ke2==4)
__device__ __forceinline__ void plane_v2(
    int ke2, int c2, int b2, int q, int wv, int lane,
    const float* wk, const __half* img, const float2* __restrict__ ob,
    float* pb, const float* __restrict__ x, const float* __restrict__ bws,
    float* __restrict__ out) {
  int p_base = wv * 576 + lane;
  int h2b = q * 48 + wv * 3;
  #pragma unroll
  for (int k = 0; k < 9; ++k) {
    int p_rel = p_base + k * 64;
    float ox = 0.0f, oy = 0.0f;
    if (MODE != 2) {
      float2 o = ob[p_rel];            // coalesced: 64 consecutive float2 per (wv,k)
      if (MODE == 1) { ox = 2.0f - o.x; oy = 2.0f - o.y; }
      else           { ox = o.x;        oy = o.y; }
    }
    int h2 = h2b + k / 3;
    int w2 = (k % 3) * 64 + lane;
    float xn = ox + (float)h2 * (1.0f / 191.0f);
    float yn = oy + (float)w2 * (1.0f / 191.0f);
    float ix = xn * 96.0f + 95.5f;
    float iy = yn * 96.0f + 95.5f;
    float prod = 0.0f;
    bool in = (ix > -1.0f) && (ix < 192.0f) && (iy > -1.0f) && (iy < 192.0f);
    bool go = (MODE == 1) ? __any(in) : true;  // sym planes mostly OOB -> wave skip
    if (go) {
      float x0f = floorf(ix), y0f = floorf(iy);
      float fx = ix - x0f, fy = iy - y0f;
      int x0 = (int)x0f, y0 = (int)y0f;
      int x1 = x0 + 1, y1 = y0 + 1;
      bool xi0 = (unsigned)x0 < 192u, xi1 = (unsigned)x1 < 192u;
      bool yi0 = (unsigned)y0 < 192u, yi1 = (unsigned)y1 < 192u;
      int xc0 = min(max(x0, 0), 191), xc1 = min(max(x1, 0), 191);
      int yc0 = min(max(y0, 0), 191), yc1 = min(max(y1, 0), 191);
      float v00 = (yi0 && xi0) ? __half2float(img[yc0 * ISTR + xc0]) : 0.0f;
      float v01 = (yi0 && xi1) ? __half2float(img[yc0 * ISTR + xc1]) : 0.0f;
      float v10 = (yi1 && xi0) ? __half2float(img[yc1 * ISTR + xc0]) : 0.0f;
      float v11 = (yi1 && xi1) ? __half2float(img[yc1 * ISTR + xc1]) : 0.0f;
      float sv = v00 * (1.0f - fy) * (1.0f - fx) + v01 * (1.0f - fy) * fx
               + v10 * fy * (1.0f - fx) + v11 * fy * fx;
      prod = wk[k] * sv;
    }
    pb[p_rel + p_rel / 144] = prod;    // swizzle: phys = s + s/144
  }
  __syncthreads();  // writers done; buffer-reuse hazard covered by dbuf + next barrier
  // reader: c = wv, w_hi = lane; output o_rel = w_hi*16 + c; phys base = 145*w_hi + 9*c
  int c = wv, w_hi = lane;
  float sum = 0.0f;
  int pbase = 145 * w_hi + 9 * c;      // stride 145 across lanes -> conflict-free
  #pragma unroll
  for (int j = 0; j < 9; ++j) sum += pb[pbase + j];
  int plane_idx = (c2 * 9 + ke2) * 4 + b2;
  int t16b = plane_idx * 256 + q * 64;
  int w0 = t16b % 192;
  int hb = t16b / 192;
  int h = hb % 192;
  int b = hb / 192;
  size_t addr = ((size_t)(b * 16 + c) * 192 + h) * 192 + w0 + w_hi;
  out[addr] = sum + bws[c] + x[addr];
}

// Grid 256: block = (imgid, quarter q).
// LDS: img 74496 | pbuf0 37120 | pbuf1 37120 = 148736 B. No reg carry across plane calls
// (1024-thr blocks cap at 64 VGPRs -- R12/R13 lesson).
__global__ __launch_bounds__(1024) void sample_kernel(
    const float* __restrict__ x, const float2* __restrict__ off2,
    const float* __restrict__ Wws, const float* __restrict__ bws,
    float* __restrict__ out) {
  extern __shared__ char smem[];
  __half* img = (__half*)smem;                    // 74496 B
  float* pbuf0 = (float*)(smem + 74496);          // 37120 B (9280 floats)
  float* pbuf1 = (float*)(smem + 111616);         // 37120 B
  int ib = blockIdx.x, tid = threadIdx.x;
  int imgid = ib >> 2, q = ib & 3;
  int b2 = imgid & 3, c2 = imgid >> 2;
  int lane = tid & 63, wv = tid >> 6;
  // per-k tap weights: depend only on p (not m/plane) -> gather once
  float wk[9];
  {
    int pb0 = q * 9216 + wv * 576 + lane;
    #pragma unroll
    for (int k = 0; k < 9; ++k) {
      int p = pb0 + k * 64;
      int ke = p % 9;
      int c = (p / 9) % 16;
      wk[k] = Wws[c * 9 + ke];
    }
  }
  // stage image f32 -> f16, row stride 194 halves (validated)
  const float4* xs = (const float4*)(x + (size_t)(b2 * CC + c2) * IMG_N);
  #pragma unroll
  for (int j = 0; j < 9; ++j) {
    int i4 = j * 1024 + tid;
    float4 v = xs[i4];
    int y = i4 / 48, x0 = (i4 % 48) * 4;
    __half2* ip = (__half2*)(img + y * ISTR + x0);
    ip[0] = __floats2half2_rn(v.x, v.y);
    ip[1] = __floats2half2_rn(v.z, v.w);
  }
  __syncthreads();
  int pl = 0;
  #pragma unroll 1
  for (int m = 0; m < 4; ++m) {
    const float2* ob = off2 + (size_t)((c2 * 4 + m) * 4 + b2) * IMG_N + q * 9216;
    plane_v2<0>(m, c2, b2, q, wv, lane, wk, img, ob,
                (pl & 1) ? pbuf1 : pbuf0, x, bws, out);
    ++pl;
    plane_v2<1>(m + 5, c2, b2, q, wv, lane, wk, img, ob,
                (pl & 1) ? pbuf1 : pbuf0, x, bws, out);
    ++pl;
  }
  plane_v2<2>(4, c2, b2, q, wv, lane, wk, img, (const float2*)nullptr,
              (pl & 1) ? pbuf1 : pbuf0, x, bws, out);
}

extern "C" void kernel_launch(void* const* d_in, const int* in_sizes, int n_in,
                              void* d_out, int out_size, void* d_ws, size_t ws_size,
                              hipStream_t stream) {
  (void)in_sizes; (void)n_in; (void)out_size; (void)ws_size;
  const float* x    = (const float*)d_in[0];
  const float* Wref = (const float*)d_in[1];
  const float* bref = (const float*)d_in[2];
  const float* Wws  = (const float*)d_in[3];
  const float* bws  = (const float*)d_in[4];
  float* out = (float*)d_out;
  uint* Wpack = (uint*)d_ws;                           // 73728 B
  float2* off2 = (float2*)((char*)d_ws + 73728);       // 75497472 B

  hipFuncSetAttribute(reinterpret_cast<const void*>(sample_kernel),
                      hipFuncAttributeMaxDynamicSharedMemorySize, 148736);
  prepack_w_kernel<<<9, 256, 0, stream>>>(Wref, Wpack);
  conv_kernel<<<1152, 256, 0, stream>>>(x, Wpack, bref, off2);
  sample_kernel<<<256, 1024, 148736, stream>>>(x, off2, Wws, bws, out);
}

// Round 17
// 84.638 us; speedup vs baseline: 1.3498x; 1.3498x over previous
//
#include <hip/hip_runtime.h>
#include <hip/hip_fp16.h>

// Seesaw_Conv: 3x3 conv (16->128) offsets -> scrambled bilinear sampling -> 9-tap weighted sum + residual
// B=4, C=16, H=W=192, K=3, KE=9, M=4
// ws layout: [0,73728): Wpack (f16 hi/lo B-fragments); [73728,+75497472): off2 float2[64][4][192][192]
// Conv: MFMA implicit GEMM, 512-thr block = 2 rows x 64 w x 128 co, 8 waves; per-wave shape
// identical to R14's spill-free 64-cout config (acc[4][2] + one WF cur/nxt pair).
// GRID = 3 x 96 x 4 = 1152 (R16 bug: launched 576 -> batches 2,3 never written).
// Sampler V2 (R14) + FMA-folded coordinates (cx/cy per-k constants).

#define HH 192
#define WW 192
#define CC 16
#define CO 128
#define IMG_N (HH * WW)
#define ISTR 194  // img LDS row stride in halves (97 dwords, odd -> bank-clean)
#define XSTR 10   // dwords per (row,col) cell in conv packed x-tile

typedef _Float16 f16x8 __attribute__((ext_vector_type(8)));
typedef float f32x4 __attribute__((ext_vector_type(4)));
typedef uint u32x4 __attribute__((ext_vector_type(4)));

static __device__ __forceinline__ f16x8 ld_frag_global(const uint* p) {
  u32x4 v = *(const u32x4*)p;
  return __builtin_bit_cast(f16x8, v);
}

// Prepack W into MFMA B-fragment order, f16 hi+lo. (validated)
__global__ __launch_bounds__(256) void prepack_w_kernel(
    const float* __restrict__ Wref, uint* __restrict__ Wpack) {
  int e = blockIdx.x * 256 + threadIdx.x;
  if (e >= 2304) return;
  int s, btg, l;
  if (e < 2048) { s = e >> 9; int rem = e & 511; btg = rem >> 6; l = rem & 63; }
  else { s = 4; int rem = e - 2048; btg = rem >> 5; l = rem & 31; }
  int g = l >> 4;
  int tap = s * 2 + (g >> 1);
  int co = btg * 16 + (l & 15);
  int cin0 = (g & 1) * 8;
  int kh = (tap * 11) >> 5;
  int kw = tap - 3 * kh;
  uint hd[4], ld[4];
  #pragma unroll
  for (int j = 0; j < 4; ++j) {
    uint hh[2], ll[2];
    #pragma unroll
    for (int q = 0; q < 2; ++q) {
      int i = 2 * j + q;
      float v = Wref[((co * CC + cin0 + i) * 3 + kh) * 3 + kw];
      __half h = __float2half(v);
      __half lo = __float2half(v - __half2float(h));
      hh[q] = __half_as_ushort(h);
      ll[q] = __half_as_ushort(lo);
    }
    hd[j] = hh[0] | (hh[1] << 16);
    ld[j] = ll[0] | (ll[1] << 16);
  }
  uint base = (e < 2048) ? (uint)e * 8u : 16384u + (uint)(btg * 32 + l) * 8u;
  #pragma unroll
  for (int j = 0; j < 4; ++j) { Wpack[base + j] = hd[j]; Wpack[base + 4 + j] = ld[j]; }
}

struct WF { f16x8 bh0, bl0, bh1, bl1; };

static __device__ __forceinline__ WF load_w(const uint* __restrict__ Wpack,
                                            int s, int btg0, int l) {
  WF f;
  u32x4 z4 = {0, 0, 0, 0};
  f.bh0 = __builtin_bit_cast(f16x8, z4);
  f.bl0 = f.bh0; f.bh1 = f.bh0; f.bl1 = f.bh0;
  if (s < 4) {
    const uint* bp0 = Wpack + (size_t)((s * 8 + btg0) * 64 + l) * 8;
    f.bh0 = ld_frag_global(bp0);
    f.bl0 = ld_frag_global(bp0 + 4);
    const uint* bp1 = Wpack + (size_t)((s * 8 + btg0 + 1) * 64 + l) * 8;
    f.bh1 = ld_frag_global(bp1);
    f.bl1 = ld_frag_global(bp1 + 4);
  } else if (l < 32) {
    const uint* bp0 = Wpack + 16384 + (size_t)(btg0 * 32 + l) * 8;
    f.bh0 = ld_frag_global(bp0);
    f.bl0 = ld_frag_global(bp0 + 4);
    const uint* bp1 = Wpack + 16384 + (size_t)((btg0 + 1) * 32 + l) * 8;
    f.bh1 = ld_frag_global(bp1);
    f.bl1 = ld_frag_global(bp1 + 4);
  }
  return f;
}

// MFMA conv. Block: 2 rows x 64 w x 128 co, 512 thr = 8 waves.
// Wave wv: r = wv&1 (row), wn = wv>>1 (32-cout group, btg0 = wn*2).
// Per-wave live set == R14's validated spill-free config.
__global__ __launch_bounds__(512, 2) void conv_kernel(
    const float* __restrict__ x, const uint* __restrict__ Wpack,
    const float* __restrict__ bref, float2* __restrict__ off2) {
  __shared__ uint smem[2 * 2640];  // XH | XL (21120 B); epilogue reuse: float sb[128*33]
  uint* XH = smem;
  uint* XL = smem + 2640;
  int bid = blockIdx.x;
  int wt_ = bid % 3;
  int hp = (bid / 3) % 96;
  int b = bid / 288;              // grid 1152 -> b in 0..3
  int w0 = wt_ * 64, h0 = hp * 2;
  int t = threadIdx.x;
  int l = t & 63, wv = t >> 6;
  int r = wv & 1, wn = wv >> 1;
  int g = l >> 4, l15 = l & 15;
  int btg0 = wn * 2;

  WF cur = load_w(Wpack, 0, btg0, l);  // overlaps x staging

  for (int idx = t; idx < 2112; idx += 512) {
    int cp = idx / 264;
    int rem = idx - cp * 264;
    int row = rem / 66;
    int col = rem - row * 66;
    int gh = h0 + row - 1, gw = w0 + col - 1;
    float v0 = 0.0f, v1 = 0.0f;
    if ((unsigned)gh < 192u && (unsigned)gw < 192u) {
      const float* gp = x + ((size_t)(b * CC + 2 * cp) * HH + gh) * WW + gw;
      v0 = gp[0];
      v1 = gp[IMG_N];
    }
    __half ha = __float2half(v0), hb = __float2half(v1);
    __half la = __float2half(v0 - __half2float(ha));
    __half lb = __float2half(v1 - __half2float(hb));
    int a = (row * 66 + col) * XSTR + cp;
    XH[a] = (uint)__half_as_ushort(ha) | ((uint)__half_as_ushort(hb) << 16);
    XL[a] = (uint)__half_as_ushort(la) | ((uint)__half_as_ushort(lb) << 16);
  }

  int base0 = (r * 66 + l15) * XSTR + (g & 1) * 4;
  int tapl = g >> 1;
  f32x4 acc[4][2];
  #pragma unroll
  for (int af = 0; af < 4; ++af)
    #pragma unroll
    for (int bt = 0; bt < 2; ++bt) acc[af][bt] = (f32x4){0.f, 0.f, 0.f, 0.f};

  __syncthreads();

  #pragma unroll 1
  for (int s = 0; s < 5; ++s) {
    WF nxt = cur;
    if (s < 4) nxt = load_w(Wpack, s + 1, btg0, l);  // issue early; waits land next iter
    int tap = s * 2 + tapl;
    if (tap > 8) tap = 8;
    int kh = (tap * 11) >> 5;
    int kw = tap - 3 * kh;
    int delta = (kh * 66 + kw) * XSTR;
    #pragma unroll
    for (int af = 0; af < 4; ++af) {
      int ap = base0 + af * (16 * XSTR) + delta;
      uint2 h01 = *(const uint2*)&XH[ap];
      uint2 h23 = *(const uint2*)&XH[ap + 2];
      uint2 l01 = *(const uint2*)&XL[ap];
      uint2 l23 = *(const uint2*)&XL[ap + 2];
      u32x4 th = {h01.x, h01.y, h23.x, h23.y};
      u32x4 tl = {l01.x, l01.y, l23.x, l23.y};
      f16x8 ah = __builtin_bit_cast(f16x8, th);
      f16x8 al = __builtin_bit_cast(f16x8, tl);
      acc[af][0] = __builtin_amdgcn_mfma_f32_16x16x32_f16(ah, cur.bh0, acc[af][0], 0, 0, 0);
      acc[af][0] = __builtin_amdgcn_mfma_f32_16x16x32_f16(ah, cur.bl0, acc[af][0], 0, 0, 0);
      acc[af][0] = __builtin_amdgcn_mfma_f32_16x16x32_f16(al, cur.bh0, acc[af][0], 0, 0, 0);
      acc[af][1] = __builtin_amdgcn_mfma_f32_16x16x32_f16(ah, cur.bh1, acc[af][1], 0, 0, 0);
      acc[af][1] = __builtin_amdgcn_mfma_f32_16x16x32_f16(ah, cur.bl1, acc[af][1], 0, 0, 0);
      acc[af][1] = __builtin_amdgcn_mfma_f32_16x16x32_f16(al, cur.bh1, acc[af][1], 0, 0, 0);
    }
    cur = nxt;
  }

  // epilogue: bias + pair-planar store via LDS transpose (sb shared across 8 waves)
  float bias[2];
  #pragma unroll
  for (int bt = 0; bt < 2; ++bt) bias[bt] = bref[wn * 32 + bt * 16 + l15];
  float* sb = (float*)smem;
  int fx = t & 63, pl_a = t >> 6;  // pl_a in 0..7
  #pragma unroll 1
  for (int c = 0; c < 4; ++c) {
    __syncthreads();
    if (wn == c) {
      #pragma unroll
      for (int bt = 0; bt < 2; ++bt)
        #pragma unroll
        for (int af = 0; af < 4; ++af)
          #pragma unroll
          for (int reg = 0; reg < 4; ++reg) {
            int px = r * 64 + af * 16 + g * 4 + reg;  // C/D: row=(l>>4)*4+reg, col=l&15
            sb[px * 33 + bt * 16 + l15] = acc[af][bt][reg] + bias[bt];
          }
    }
    __syncthreads();
    // 512 threads store 128 px x 16 pairs: thread handles pairs pl_a and pl_a+8 at px0=2*fx
    int px0 = 2 * fx;
    int rr = fx >> 5;
    int wl = px0 & 63;
    #pragma unroll
    for (int e2 = 0; e2 < 2; ++e2) {
      int p = pl_a + e2 * 8;
      int pair = c * 16 + p;
      float2* gb = off2 + ((size_t)(pair * 4 + b) * IMG_N) + (h0 + rr) * WW + w0 + wl;
      float4 v = {sb[px0 * 33 + 2 * p], sb[px0 * 33 + 2 * p + 1],
                  sb[(px0 + 1) * 33 + 2 * p], sb[(px0 + 1) * 33 + 2 * p + 1]};
      *(float4*)gb = v;
    }
  }
}

// Sampler V2 plane processor (R14 structure) + FMA-folded coords.
template <int MODE>  // 0 = normal (ke2<4), 1 = sym (ke2>4), 2 = center (ke2==4)
__device__ __forceinline__ void plane_v2(
    int ke2, int c2, int b2, int q, int wv, int lane,
    const float* wk, const float* cx, const float* cy,
    const __half* img, const float2* __restrict__ ob,
    float* pb, const float* __restrict__ x, const float* __restrict__ bws,
    float* __restrict__ out) {
  int p_base = wv * 576 + lane;
  #pragma unroll
  for (int k = 0; k < 9; ++k) {
    int p_rel = p_base + k * 64;
    float ox = 0.0f, oy = 0.0f;
    if (MODE != 2) {
      float2 o = ob[p_rel];            // coalesced: 64 consecutive float2 per (wv,k)
      if (MODE == 1) { ox = 2.0f - o.x; oy = 2.0f - o.y; }
      else           { ox = o.x;        oy = o.y; }
    }
    float ix = ox * 96.0f + cx[k];
    float iy = oy * 96.0f + cy[k];
    float prod = 0.0f;
    bool in = (ix > -1.0f) && (ix < 192.0f) && (iy > -1.0f) && (iy < 192.0f);
    bool go = (MODE == 1) ? __any(in) : true;  // sym planes mostly OOB -> wave skip
    if (go) {
      float x0f = floorf(ix), y0f = floorf(iy);
      float fxw = ix - x0f, fyw = iy - y0f;
      int x0 = (int)x0f, y0 = (int)y0f;
      int x1 = x0 + 1, y1 = y0 + 1;
      bool xi0 = (unsigned)x0 < 192u, xi1 = (unsigned)x1 < 192u;
      bool yi0 = (unsigned)y0 < 192u, yi1 = (unsigned)y1 < 192u;
      int xc0 = min(max(x0, 0), 191), xc1 = min(max(x1, 0), 191);
      int yc0 = min(max(y0, 0), 191), yc1 = min(max(y1, 0), 191);
      float v00 = (yi0 && xi0) ? __half2float(img[yc0 * ISTR + xc0]) : 0.0f;
      float v01 = (yi0 && xi1) ? __half2float(img[yc0 * ISTR + xc1]) : 0.0f;
      float v10 = (yi1 && xi0) ? __half2float(img[yc1 * ISTR + xc0]) : 0.0f;
      float v11 = (yi1 && xi1) ? __half2float(img[yc1 * ISTR + xc1]) : 0.0f;
      float sv = v00 * (1.0f - fyw) * (1.0f - fxw) + v01 * (1.0f - fyw) * fxw
               + v10 * fyw * (1.0f - fxw) + v11 * fyw * fxw;
      prod = wk[k] * sv;
    }
    pb[p_rel + p_rel / 144] = prod;    // swizzle: phys = s + s/144
  }
  __syncthreads();  // writers done; buffer-reuse hazard covered by dbuf + next barrier
  // reader: c = wv, w_hi = lane; output o_rel = w_hi*16 + c; phys base = 145*w_hi + 9*c
  int c = wv, w_hi = lane;
  float sum = 0.0f;
  int pbase = 145 * w_hi + 9 * c;      // stride 145 across lanes -> conflict-free
  #pragma unroll
  for (int j = 0; j < 9; ++j) sum += pb[pbase + j];
  int plane_idx = (c2 * 9 + ke2) * 4 + b2;
  int t16b = plane_idx * 256 + q * 64;
  int w0 = t16b % 192;
  int hb = t16b / 192;
  int h = hb % 192;
  int b = hb / 192;
  size_t addr = ((size_t)(b * 16 + c) * 192 + h) * 192 + w0 + w_hi;
  out[addr] = sum + bws[c] + x[addr];
}

// Grid 256: block = (imgid, quarter q).
// LDS: img 74496 | pbuf0 37120 | pbuf1 37120 = 148736 B. Register carry: wk+cx+cy = 27
// (stays under the 64-VGPR cap for 1024-thr blocks -- R12/R13 lesson).
__global__ __launch_bounds__(1024) void sample_kernel(
    const float* __restrict__ x, const float2* __restrict__ off2,
    const float* __restrict__ Wws, const float* __restrict__ bws,
    float* __restrict__ out) {
  extern __shared__ char smem[];
  __half* img = (__half*)smem;                    // 74496 B
  float* pbuf0 = (float*)(smem + 74496);          // 37120 B (9280 floats)
  float* pbuf1 = (float*)(smem + 111616);         // 37120 B
  int ib = blockIdx.x, tid = threadIdx.x;
  int imgid = ib >> 2, q = ib & 3;
  int b2 = imgid & 3, c2 = imgid >> 2;
  int lane = tid & 63, wv = tid >> 6;
  // per-k constants: tap weights + folded base coords
  float wk[9], cx[9], cy[9];
  {
    int pb0 = q * 9216 + wv * 576 + lane;
    int h2b = q * 48 + wv * 3;
    #pragma unroll
    for (int k = 0; k < 9; ++k) {
      int p = pb0 + k * 64;
      int ke = p % 9;
      int c = (p / 9) % 16;
      wk[k] = Wws[c * 9 + ke];
      int h2 = h2b + k / 3;
      int w2 = (k % 3) * 64 + lane;
      cx[k] = (float)h2 * (1.0f / 191.0f) * 96.0f + 95.5f;
      cy[k] = (float)w2 * (1.0f / 191.0f) * 96.0f + 95.5f;
    }
  }
  // stage image f32 -> f16, row stride 194 halves (validated)
  const float4* xs = (const float4*)(x + (size_t)(b2 * CC + c2) * IMG_N);
  #pragma unroll
  for (int j = 0; j < 9; ++j) {
    int i4 = j * 1024 + tid;
    float4 v = xs[i4];
    int y = i4 / 48, x0 = (i4 % 48) * 4;
    __half2* ip = (__half2*)(img + y * ISTR + x0);
    ip[0] = __floats2half2_rn(v.x, v.y);
    ip[1] = __floats2half2_rn(v.z, v.w);
  }
  __syncthreads();
  int pl = 0;
  #pragma unroll 1
  for (int m = 0; m < 4; ++m) {
    const float2* ob = off2 + (size_t)((c2 * 4 + m) * 4 + b2) * IMG_N + q * 9216;
    plane_v2<0>(m, c2, b2, q, wv, lane, wk, cx, cy, img, ob,
                (pl & 1) ? pbuf1 : pbuf0, x, bws, out);
    ++pl;
    plane_v2<1>(m + 5, c2, b2, q, wv, lane, wk, cx, cy, img, ob,
                (pl & 1) ? pbuf1 : pbuf0, x, bws, out);
    ++pl;
  }
  plane_v2<2>(4, c2, b2, q, wv, lane, wk, cx, cy, img, (const float2*)nullptr,
              (pl & 1) ? pbuf1 : pbuf0, x, bws, out);
}

extern "C" void kernel_launch(void* const* d_in, const int* in_sizes, int n_in,
                              void* d_out, int out_size, void* d_ws, size_t ws_size,
                              hipStream_t stream) {
  (void)in_sizes; (void)n_in; (void)out_size; (void)ws_size;
  const float* x    = (const float*)d_in[0];
  const float* Wref = (const float*)d_in[1];
  const float* bref = (const float*)d_in[2];
  const float* Wws  = (const float*)d_in[3];
  const float* bws  = (const float*)d_in[4];
  float* out = (float*)d_out;
  uint* Wpack = (uint*)d_ws;                           // 73728 B
  float2* off2 = (float2*)((char*)d_ws + 73728);       // 75497472 B

  hipFuncSetAttribute(reinterpret_cast<const void*>(sample_kernel),
                      hipFuncAttributeMaxDynamicSharedMemorySize, 148736);
  prepack_w_kernel<<<9, 256, 0, stream>>>(Wref, Wpack);
  conv_kernel<<<1152, 512, 0, stream>>>(x, Wpack, bref, off2);
  sample_kernel<<<256, 1024, 148736, stream>>>(x, off2, Wws, bws, out);
}

// Round 18
// 79.848 us; speedup vs baseline: 1.4308x; 1.0600x over previous
//
#include <hip/hip_runtime.h>
#include <hip/hip_fp16.h>

// Seesaw_Conv: 3x3 conv (16->128) offsets -> scrambled bilinear sampling -> 9-tap weighted sum + residual
// B=4, C=16, H=W=192, K=3, KE=9, M=4
// ws layout: [0,73728): Wpack (f16 hi/lo B-fragments); [73728,+75497472): off2 float2[64][4][192][192]
// Conv: MFMA implicit GEMM, 512-thr block = 2 rows x 64 w x 128 co (R17, validated).
// Sampler V3: FUSED plane pairs -- one offset-gather pass serves both ke2=m (normal) and
// ke2=m+5 (sym, 2-off) planes; products to two swizzled pbufs, one barrier, regroup both.
// Weight index is plane-invariant (ke=pos%9, c=(pos/9)%16), so wk[] transfers unchanged.

#define HH 192
#define WW 192
#define CC 16
#define CO 128
#define IMG_N (HH * WW)
#define ISTR 194  // img LDS row stride in halves (97 dwords, odd -> bank-clean)
#define XSTR 10   // dwords per (row,col) cell in conv packed x-tile

typedef _Float16 f16x8 __attribute__((ext_vector_type(8)));
typedef float f32x4 __attribute__((ext_vector_type(4)));
typedef uint u32x4 __attribute__((ext_vector_type(4)));

static __device__ __forceinline__ f16x8 ld_frag_global(const uint* p) {
  u32x4 v = *(const u32x4*)p;
  return __builtin_bit_cast(f16x8, v);
}

// Prepack W into MFMA B-fragment order, f16 hi+lo. (validated)
__global__ __launch_bounds__(256) void prepack_w_kernel(
    const float* __restrict__ Wref, uint* __restrict__ Wpack) {
  int e = blockIdx.x * 256 + threadIdx.x;
  if (e >= 2304) return;
  int s, btg, l;
  if (e < 2048) { s = e >> 9; int rem = e & 511; btg = rem >> 6; l = rem & 63; }
  else { s = 4; int rem = e - 2048; btg = rem >> 5; l = rem & 31; }
  int g = l >> 4;
  int tap = s * 2 + (g >> 1);
  int co = btg * 16 + (l & 15);
  int cin0 = (g & 1) * 8;
  int kh = (tap * 11) >> 5;
  int kw = tap - 3 * kh;
  uint hd[4], ld[4];
  #pragma unroll
  for (int j = 0; j < 4; ++j) {
    uint hh[2], ll[2];
    #pragma unroll
    for (int q = 0; q < 2; ++q) {
      int i = 2 * j + q;
      float v = Wref[((co * CC + cin0 + i) * 3 + kh) * 3 + kw];
      __half h = __float2half(v);
      __half lo = __float2half(v - __half2float(h));
      hh[q] = __half_as_ushort(h);
      ll[q] = __half_as_ushort(lo);
    }
    hd[j] = hh[0] | (hh[1] << 16);
    ld[j] = ll[0] | (ll[1] << 16);
  }
  uint base = (e < 2048) ? (uint)e * 8u : 16384u + (uint)(btg * 32 + l) * 8u;
  #pragma unroll
  for (int j = 0; j < 4; ++j) { Wpack[base + j] = hd[j]; Wpack[base + 4 + j] = ld[j]; }
}

struct WF { f16x8 bh0, bl0, bh1, bl1; };

static __device__ __forceinline__ WF load_w(const uint* __restrict__ Wpack,
                                            int s, int btg0, int l) {
  WF f;
  u32x4 z4 = {0, 0, 0, 0};
  f.bh0 = __builtin_bit_cast(f16x8, z4);
  f.bl0 = f.bh0; f.bh1 = f.bh0; f.bl1 = f.bh0;
  if (s < 4) {
    const uint* bp0 = Wpack + (size_t)((s * 8 + btg0) * 64 + l) * 8;
    f.bh0 = ld_frag_global(bp0);
    f.bl0 = ld_frag_global(bp0 + 4);
    const uint* bp1 = Wpack + (size_t)((s * 8 + btg0 + 1) * 64 + l) * 8;
    f.bh1 = ld_frag_global(bp1);
    f.bl1 = ld_frag_global(bp1 + 4);
  } else if (l < 32) {
    const uint* bp0 = Wpack + 16384 + (size_t)(btg0 * 32 + l) * 8;
    f.bh0 = ld_frag_global(bp0);
    f.bl0 = ld_frag_global(bp0 + 4);
    const uint* bp1 = Wpack + 16384 + (size_t)((btg0 + 1) * 32 + l) * 8;
    f.bh1 = ld_frag_global(bp1);
    f.bl1 = ld_frag_global(bp1 + 4);
  }
  return f;
}

// MFMA conv (R17, validated). Block: 2 rows x 64 w x 128 co, 512 thr = 8 waves. Grid 1152.
__global__ __launch_bounds__(512, 2) void conv_kernel(
    const float* __restrict__ x, const uint* __restrict__ Wpack,
    const float* __restrict__ bref, float2* __restrict__ off2) {
  __shared__ uint smem[2 * 2640];  // XH | XL (21120 B); epilogue reuse: float sb[128*33]
  uint* XH = smem;
  uint* XL = smem + 2640;
  int bid = blockIdx.x;
  int wt_ = bid % 3;
  int hp = (bid / 3) % 96;
  int b = bid / 288;              // grid 1152 -> b in 0..3
  int w0 = wt_ * 64, h0 = hp * 2;
  int t = threadIdx.x;
  int l = t & 63, wv = t >> 6;
  int r = wv & 1, wn = wv >> 1;
  int g = l >> 4, l15 = l & 15;
  int btg0 = wn * 2;

  WF cur = load_w(Wpack, 0, btg0, l);  // overlaps x staging

  for (int idx = t; idx < 2112; idx += 512) {
    int cp = idx / 264;
    int rem = idx - cp * 264;
    int row = rem / 66;
    int col = rem - row * 66;
    int gh = h0 + row - 1, gw = w0 + col - 1;
    float v0 = 0.0f, v1 = 0.0f;
    if ((unsigned)gh < 192u && (unsigned)gw < 192u) {
      const float* gp = x + ((size_t)(b * CC + 2 * cp) * HH + gh) * WW + gw;
      v0 = gp[0];
      v1 = gp[IMG_N];
    }
    __half ha = __float2half(v0), hb = __float2half(v1);
    __half la = __float2half(v0 - __half2float(ha));
    __half lb = __float2half(v1 - __half2float(hb));
    int a = (row * 66 + col) * XSTR + cp;
    XH[a] = (uint)__half_as_ushort(ha) | ((uint)__half_as_ushort(hb) << 16);
    XL[a] = (uint)__half_as_ushort(la) | ((uint)__half_as_ushort(lb) << 16);
  }

  int base0 = (r * 66 + l15) * XSTR + (g & 1) * 4;
  int tapl = g >> 1;
  f32x4 acc[4][2];
  #pragma unroll
  for (int af = 0; af < 4; ++af)
    #pragma unroll
    for (int bt = 0; bt < 2; ++bt) acc[af][bt] = (f32x4){0.f, 0.f, 0.f, 0.f};

  __syncthreads();

  #pragma unroll 1
  for (int s = 0; s < 5; ++s) {
    WF nxt = cur;
    if (s < 4) nxt = load_w(Wpack, s + 1, btg0, l);  // issue early; waits land next iter
    int tap = s * 2 + tapl;
    if (tap > 8) tap = 8;
    int kh = (tap * 11) >> 5;
    int kw = tap - 3 * kh;
    int delta = (kh * 66 + kw) * XSTR;
    #pragma unroll
    for (int af = 0; af < 4; ++af) {
      int ap = base0 + af * (16 * XSTR) + delta;
      uint2 h01 = *(const uint2*)&XH[ap];
      uint2 h23 = *(const uint2*)&XH[ap + 2];
      uint2 l01 = *(const uint2*)&XL[ap];
      uint2 l23 = *(const uint2*)&XL[ap + 2];
      u32x4 th = {h01.x, h01.y, h23.x, h23.y};
      u32x4 tl = {l01.x, l01.y, l23.x, l23.y};
      f16x8 ah = __builtin_bit_cast(f16x8, th);
      f16x8 al = __builtin_bit_cast(f16x8, tl);
      acc[af][0] = __builtin_amdgcn_mfma_f32_16x16x32_f16(ah, cur.bh0, acc[af][0], 0, 0, 0);
      acc[af][0] = __builtin_amdgcn_mfma_f32_16x16x32_f16(ah, cur.bl0, acc[af][0], 0, 0, 0);
      acc[af][0] = __builtin_amdgcn_mfma_f32_16x16x32_f16(al, cur.bh0, acc[af][0], 0, 0, 0);
      acc[af][1] = __builtin_amdgcn_mfma_f32_16x16x32_f16(ah, cur.bh1, acc[af][1], 0, 0, 0);
      acc[af][1] = __builtin_amdgcn_mfma_f32_16x16x32_f16(ah, cur.bl1, acc[af][1], 0, 0, 0);
      acc[af][1] = __builtin_amdgcn_mfma_f32_16x16x32_f16(al, cur.bh1, acc[af][1], 0, 0, 0);
    }
    cur = nxt;
  }

  // epilogue: bias + pair-planar store via LDS transpose (sb shared across 8 waves)
  float bias[2];
  #pragma unroll
  for (int bt = 0; bt < 2; ++bt) bias[bt] = bref[wn * 32 + bt * 16 + l15];
  float* sb = (float*)smem;
  int fx = t & 63, pl_a = t >> 6;  // pl_a in 0..7
  #pragma unroll 1
  for (int c = 0; c < 4; ++c) {
    __syncthreads();
    if (wn == c) {
      #pragma unroll
      for (int bt = 0; bt < 2; ++bt)
        #pragma unroll
        for (int af = 0; af < 4; ++af)
          #pragma unroll
          for (int reg = 0; reg < 4; ++reg) {
            int px = r * 64 + af * 16 + g * 4 + reg;  // C/D: row=(l>>4)*4+reg, col=l&15
            sb[px * 33 + bt * 16 + l15] = acc[af][bt][reg] + bias[bt];
          }
    }
    __syncthreads();
    // 512 threads store 128 px x 16 pairs: thread handles pairs pl_a and pl_a+8 at px0=2*fx
    int px0 = 2 * fx;
    int rr = fx >> 5;
    int wl = px0 & 63;
    #pragma unroll
    for (int e2 = 0; e2 < 2; ++e2) {
      int p = pl_a + e2 * 8;
      int pair = c * 16 + p;
      float2* gb = off2 + ((size_t)(pair * 4 + b) * IMG_N) + (h0 + rr) * WW + w0 + wl;
      float4 v = {sb[px0 * 33 + 2 * p], sb[px0 * 33 + 2 * p + 1],
                  sb[(px0 + 1) * 33 + 2 * p], sb[(px0 + 1) * 33 + 2 * p + 1]};
      *(float4*)gb = v;
    }
  }
}

// Bilinear tap from LDS f16 image (R17-validated arithmetic, op-for-op).
static __device__ __forceinline__ float tap_img(const __half* img, float ix, float iy) {
  float x0f = floorf(ix), y0f = floorf(iy);
  float fxw = ix - x0f, fyw = iy - y0f;
  int x0 = (int)x0f, y0 = (int)y0f;
  int x1 = x0 + 1, y1 = y0 + 1;
  bool xi0 = (unsigned)x0 < 192u, xi1 = (unsigned)x1 < 192u;
  bool yi0 = (unsigned)y0 < 192u, yi1 = (unsigned)y1 < 192u;
  int xc0 = min(max(x0, 0), 191), xc1 = min(max(x1, 0), 191);
  int yc0 = min(max(y0, 0), 191), yc1 = min(max(y1, 0), 191);
  float v00 = (yi0 && xi0) ? __half2float(img[yc0 * ISTR + xc0]) : 0.0f;
  float v01 = (yi0 && xi1) ? __half2float(img[yc0 * ISTR + xc1]) : 0.0f;
  float v10 = (yi1 && xi0) ? __half2float(img[yc1 * ISTR + xc0]) : 0.0f;
  float v11 = (yi1 && xi1) ? __half2float(img[yc1 * ISTR + xc1]) : 0.0f;
  return v00 * (1.0f - fyw) * (1.0f - fxw) + v01 * (1.0f - fyw) * fxw
       + v10 * fyw * (1.0f - fxw) + v11 * fyw * fxw;
}

// Fused plane-pair processor. MODE 0: one gather pass serves planes ke2=m (normal, ->pbA)
// and ke2=m+5 (sym 2-off, ->pbB); regroup + write BOTH after one barrier.
// MODE 2: center plane (zero offset) -> pbA only.
template <int MODE>
__device__ __forceinline__ void plane_pair(
    int m, int c2, int b2, int q, int wv, int lane,
    const float* wk, const float* cx, const float* cy,
    const __half* img, const float2* __restrict__ ob,
    float* pbA, float* pbB,
    const float* __restrict__ x, const float* __restrict__ bws,
    float* __restrict__ out) {
  int p_base = wv * 576 + lane;
  #pragma unroll
  for (int k = 0; k < 9; ++k) {
    int p_rel = p_base + k * 64;
    int phys = p_rel + p_rel / 144;   // swizzle: stride-145 reads, conflict-free
    if (MODE == 2) {
      pbA[phys] = wk[k] * tap_img(img, cx[k], cy[k]);
    } else {
      float2 o = ob[p_rel];           // coalesced: 64 consecutive float2 per (wv,k)
      float ixN = o.x * 96.0f + cx[k];
      float iyN = o.y * 96.0f + cy[k];
      pbA[phys] = wk[k] * tap_img(img, ixN, iyN);
      float oxS = 2.0f - o.x, oyS = 2.0f - o.y;
      float ixS = oxS * 96.0f + cx[k];
      float iyS = oyS * 96.0f + cy[k];
      float prodS = 0.0f;
      bool inS = (ixS > -1.0f) && (ixS < 192.0f) && (iyS > -1.0f) && (iyS < 192.0f);
      if (__any(inS))                 // sym taps ~99.8% OOB -> wave skip
        prodS = wk[k] * tap_img(img, ixS, iyS);
      pbB[phys] = prodS;
    }
  }
  __syncthreads();  // products visible; caller barriers before pbuf reuse
  // regroup: output (c=wv, w_hi=lane) sums products at s = 144*w_hi + 9*c .. +8
  int c = wv, w_hi = lane;
  int pbase = 145 * w_hi + 9 * c;     // phys of s=144*w_hi+9c; stride 145 -> conflict-free
  float sumA = 0.0f, sumB = 0.0f;
  #pragma unroll
  for (int j = 0; j < 9; ++j) {
    sumA += pbA[pbase + j];
    if (MODE != 2) sumB += pbB[pbase + j];
  }
  int ke2A = (MODE == 2) ? 4 : m;
  {
    int plane_idx = (c2 * 9 + ke2A) * 4 + b2;
    int t16b = plane_idx * 256 + q * 64;
    int w0 = t16b % 192;
    int hb = t16b / 192;
    int h = hb % 192;
    int b = hb / 192;
    size_t addr = ((size_t)(b * 16 + c) * 192 + h) * 192 + w0 + w_hi;
    out[addr] = sumA + bws[c] + x[addr];
  }
  if (MODE != 2) {
    int plane_idx = (c2 * 9 + m + 5) * 4 + b2;
    int t16b = plane_idx * 256 + q * 64;
    int w0 = t16b % 192;
    int hb = t16b / 192;
    int h = hb % 192;
    int b = hb / 192;
    size_t addr = ((size_t)(b * 16 + c) * 192 + h) * 192 + w0 + w_hi;
    out[addr] = sumB + bws[c] + x[addr];
  }
}

// Grid 256: block = (imgid, quarter q).
// LDS: img 74496 | pbufA 37120 | pbufB 37120 = 148736 B. No reg carry across plane calls
// beyond wk/cx/cy (27) -- 1024-thr blocks cap at 64 VGPRs (R12/R13 lesson).
__global__ __launch_bounds__(1024) void sample_kernel(
    const float* __restrict__ x, const float2* __restrict__ off2,
    const float* __restrict__ Wws, const float* __restrict__ bws,
    float* __restrict__ out) {
  extern __shared__ char smem[];
  __half* img = (__half*)smem;                    // 74496 B
  float* pbufA = (float*)(smem + 74496);          // 37120 B (9280 floats)
  float* pbufB = (float*)(smem + 111616);         // 37120 B
  int ib = blockIdx.x, tid = threadIdx.x;
  int imgid = ib >> 2, q = ib & 3;
  int b2 = imgid & 3, c2 = imgid >> 2;
  int lane = tid & 63, wv = tid >> 6;
  // per-k constants: tap weights + folded base coords (plane-invariant)
  float wk[9], cx[9], cy[9];
  {
    int pb0 = q * 9216 + wv * 576 + lane;
    int h2b = q * 48 + wv * 3;
    #pragma unroll
    for (int k = 0; k < 9; ++k) {
      int p = pb0 + k * 64;
      int ke = p % 9;
      int c = (p / 9) % 16;
      wk[k] = Wws[c * 9 + ke];
      int h2 = h2b + k / 3;
      int w2 = (k % 3) * 64 + lane;
      cx[k] = (float)h2 * (1.0f / 191.0f) * 96.0f + 95.5f;
      cy[k] = (float)w2 * (1.0f / 191.0f) * 96.0f + 95.5f;
    }
  }
  // stage image f32 -> f16, row stride 194 halves (validated)
  const float4* xs = (const float4*)(x + (size_t)(b2 * CC + c2) * IMG_N);
  #pragma unroll
  for (int j = 0; j < 9; ++j) {
    int i4 = j * 1024 + tid;
    float4 v = xs[i4];
    int y = i4 / 48, x0 = (i4 % 48) * 4;
    __half2* ip = (__half2*)(img + y * ISTR + x0);
    ip[0] = __floats2half2_rn(v.x, v.y);
    ip[1] = __floats2half2_rn(v.z, v.w);
  }
  __syncthreads();
  #pragma unroll 1
  for (int m = 0; m < 4; ++m) {
    if (m) __syncthreads();  // previous regroup readers done before pbuf overwrite
    const float2* ob = off2 + (size_t)((c2 * 4 + m) * 4 + b2) * IMG_N + q * 9216;
    plane_pair<0>(m, c2, b2, q, wv, lane, wk, cx, cy, img, ob, pbufA, pbufB, x, bws, out);
  }
  __syncthreads();
  plane_pair<2>(0, c2, b2, q, wv, lane, wk, cx, cy, img, (const float2*)nullptr,
                pbufA, pbufB, x, bws, out);
}

extern "C" void kernel_launch(void* const* d_in, const int* in_sizes, int n_in,
                              void* d_out, int out_size, void* d_ws, size_t ws_size,
                              hipStream_t stream) {
  (void)in_sizes; (void)n_in; (void)out_size; (void)ws_size;
  const float* x    = (const float*)d_in[0];
  const float* Wref = (const float*)d_in[1];
  const float* bref = (const float*)d_in[2];
  const float* Wws  = (const float*)d_in[3];
  const float* bws  = (const float*)d_in[4];
  float* out = (float*)d_out;
  uint* Wpack = (uint*)d_ws;                           // 73728 B
  float2* off2 = (float2*)((char*)d_ws + 73728);       // 75497472 B

  hipFuncSetAttribute(reinterpret_cast<const void*>(sample_kernel),
                      hipFuncAttributeMaxDynamicSharedMemorySize, 148736);
  prepack_w_kernel<<<9, 256, 0, stream>>>(Wref, Wpack);
  conv_kernel<<<1152, 512, 0, stream>>>(x, Wpack, bref, off2);
  sample_kernel<<<256, 1024, 148736, stream>>>(x, off2, Wws, bws, out);
}

// Round 19
// 74.353 us; speedup vs baseline: 1.5366x; 1.0739x over previous
//
#include <hip/hip_runtime.h>
#include <hip/hip_fp16.h>

// Seesaw_Conv: 3x3 conv (16->128) offsets -> scrambled bilinear sampling -> 9-tap weighted sum + residual
// B=4, C=16, H=W=192, K=3, KE=9, M=4
// ws layout: [0,73728): Wpack (f16 hi/lo B-fragments); [73728,+37748736): offh uint[64][4][192][192]
//   (packed half2: lo=ox, hi=oy) -- f16 offsets halve conv-write + sampler-read traffic.
// Conv: MFMA implicit GEMM, 512-thr block = 2 rows x 64 w x 128 co (R17, validated).
// Sampler V3 (R18, validated): fused plane pairs, one gather pass -> both ke2=m and m+5.

#define HH 192
#define WW 192
#define CC 16
#define CO 128
#define IMG_N (HH * WW)
#define ISTR 194  // img LDS row stride in halves (97 dwords, odd -> bank-clean)
#define XSTR 10   // dwords per (row,col) cell in conv packed x-tile

typedef _Float16 f16x8 __attribute__((ext_vector_type(8)));
typedef float f32x4 __attribute__((ext_vector_type(4)));
typedef uint u32x4 __attribute__((ext_vector_type(4)));

static __device__ __forceinline__ f16x8 ld_frag_global(const uint* p) {
  u32x4 v = *(const u32x4*)p;
  return __builtin_bit_cast(f16x8, v);
}

// Prepack W into MFMA B-fragment order, f16 hi+lo. (validated)
__global__ __launch_bounds__(256) void prepack_w_kernel(
    const float* __restrict__ Wref, uint* __restrict__ Wpack) {
  int e = blockIdx.x * 256 + threadIdx.x;
  if (e >= 2304) return;
  int s, btg, l;
  if (e < 2048) { s = e >> 9; int rem = e & 511; btg = rem >> 6; l = rem & 63; }
  else { s = 4; int rem = e - 2048; btg = rem >> 5; l = rem & 31; }
  int g = l >> 4;
  int tap = s * 2 + (g >> 1);
  int co = btg * 16 + (l & 15);
  int cin0 = (g & 1) * 8;
  int kh = (tap * 11) >> 5;
  int kw = tap - 3 * kh;
  uint hd[4], ld[4];
  #pragma unroll
  for (int j = 0; j < 4; ++j) {
    uint hh[2], ll[2];
    #pragma unroll
    for (int q = 0; q < 2; ++q) {
      int i = 2 * j + q;
      float v = Wref[((co * CC + cin0 + i) * 3 + kh) * 3 + kw];
      __half h = __float2half(v);
      __half lo = __float2half(v - __half2float(h));
      hh[q] = __half_as_ushort(h);
      ll[q] = __half_as_ushort(lo);
    }
    hd[j] = hh[0] | (hh[1] << 16);
    ld[j] = ll[0] | (ll[1] << 16);
  }
  uint base = (e < 2048) ? (uint)e * 8u : 16384u + (uint)(btg * 32 + l) * 8u;
  #pragma unroll
  for (int j = 0; j < 4; ++j) { Wpack[base + j] = hd[j]; Wpack[base + 4 + j] = ld[j]; }
}

struct WF { f16x8 bh0, bl0, bh1, bl1; };

static __device__ __forceinline__ WF load_w(const uint* __restrict__ Wpack,
                                            int s, int btg0, int l) {
  WF f;
  u32x4 z4 = {0, 0, 0, 0};
  f.bh0 = __builtin_bit_cast(f16x8, z4);
  f.bl0 = f.bh0; f.bh1 = f.bh0; f.bl1 = f.bh0;
  if (s < 4) {
    const uint* bp0 = Wpack + (size_t)((s * 8 + btg0) * 64 + l) * 8;
    f.bh0 = ld_frag_global(bp0);
    f.bl0 = ld_frag_global(bp0 + 4);
    const uint* bp1 = Wpack + (size_t)((s * 8 + btg0 + 1) * 64 + l) * 8;
    f.bh1 = ld_frag_global(bp1);
    f.bl1 = ld_frag_global(bp1 + 4);
  } else if (l < 32) {
    const uint* bp0 = Wpack + 16384 + (size_t)(btg0 * 32 + l) * 8;
    f.bh0 = ld_frag_global(bp0);
    f.bl0 = ld_frag_global(bp0 + 4);
    const uint* bp1 = Wpack + 16384 + (size_t)((btg0 + 1) * 32 + l) * 8;
    f.bh1 = ld_frag_global(bp1);
    f.bl1 = ld_frag_global(bp1 + 4);
  }
  return f;
}

// MFMA conv (R17 structure). Block: 2 rows x 64 w x 128 co, 512 thr = 8 waves. Grid 1152.
// Epilogue stores packed half2 offsets (uint per pixel-pair-component).
__global__ __launch_bounds__(512, 2) void conv_kernel(
    const float* __restrict__ x, const uint* __restrict__ Wpack,
    const float* __restrict__ bref, uint* __restrict__ offh) {
  __shared__ uint smem[2 * 2640];  // XH | XL (21120 B); epilogue reuse: float sb[128*33]
  uint* XH = smem;
  uint* XL = smem + 2640;
  int bid = blockIdx.x;
  int wt_ = bid % 3;
  int hp = (bid / 3) % 96;
  int b = bid / 288;              // grid 1152 -> b in 0..3
  int w0 = wt_ * 64, h0 = hp * 2;
  int t = threadIdx.x;
  int l = t & 63, wv = t >> 6;
  int r = wv & 1, wn = wv >> 1;
  int g = l >> 4, l15 = l & 15;
  int btg0 = wn * 2;

  WF cur = load_w(Wpack, 0, btg0, l);  // overlaps x staging

  for (int idx = t; idx < 2112; idx += 512) {
    int cp = idx / 264;
    int rem = idx - cp * 264;
    int row = rem / 66;
    int col = rem - row * 66;
    int gh = h0 + row - 1, gw = w0 + col - 1;
    float v0 = 0.0f, v1 = 0.0f;
    if ((unsigned)gh < 192u && (unsigned)gw < 192u) {
      const float* gp = x + ((size_t)(b * CC + 2 * cp) * HH + gh) * WW + gw;
      v0 = gp[0];
      v1 = gp[IMG_N];
    }
    __half ha = __float2half(v0), hb = __float2half(v1);
    __half la = __float2half(v0 - __half2float(ha));
    __half lb = __float2half(v1 - __half2float(hb));
    int a = (row * 66 + col) * XSTR + cp;
    XH[a] = (uint)__half_as_ushort(ha) | ((uint)__half_as_ushort(hb) << 16);
    XL[a] = (uint)__half_as_ushort(la) | ((uint)__half_as_ushort(lb) << 16);
  }

  int base0 = (r * 66 + l15) * XSTR + (g & 1) * 4;
  int tapl = g >> 1;
  f32x4 acc[4][2];
  #pragma unroll
  for (int af = 0; af < 4; ++af)
    #pragma unroll
    for (int bt = 0; bt < 2; ++bt) acc[af][bt] = (f32x4){0.f, 0.f, 0.f, 0.f};

  __syncthreads();

  #pragma unroll 1
  for (int s = 0; s < 5; ++s) {
    WF nxt = cur;
    if (s < 4) nxt = load_w(Wpack, s + 1, btg0, l);  // issue early; waits land next iter
    int tap = s * 2 + tapl;
    if (tap > 8) tap = 8;
    int kh = (tap * 11) >> 5;
    int kw = tap - 3 * kh;
    int delta = (kh * 66 + kw) * XSTR;
    #pragma unroll
    for (int af = 0; af < 4; ++af) {
      int ap = base0 + af * (16 * XSTR) + delta;
      uint2 h01 = *(const uint2*)&XH[ap];
      uint2 h23 = *(const uint2*)&XH[ap + 2];
      uint2 l01 = *(const uint2*)&XL[ap];
      uint2 l23 = *(const uint2*)&XL[ap + 2];
      u32x4 th = {h01.x, h01.y, h23.x, h23.y};
      u32x4 tl = {l01.x, l01.y, l23.x, l23.y};
      f16x8 ah = __builtin_bit_cast(f16x8, th);
      f16x8 al = __builtin_bit_cast(f16x8, tl);
      acc[af][0] = __builtin_amdgcn_mfma_f32_16x16x32_f16(ah, cur.bh0, acc[af][0], 0, 0, 0);
      acc[af][0] = __builtin_amdgcn_mfma_f32_16x16x32_f16(ah, cur.bl0, acc[af][0], 0, 0, 0);
      acc[af][0] = __builtin_amdgcn_mfma_f32_16x16x32_f16(al, cur.bh0, acc[af][0], 0, 0, 0);
      acc[af][1] = __builtin_amdgcn_mfma_f32_16x16x32_f16(ah, cur.bh1, acc[af][1], 0, 0, 0);
      acc[af][1] = __builtin_amdgcn_mfma_f32_16x16x32_f16(ah, cur.bl1, acc[af][1], 0, 0, 0);
      acc[af][1] = __builtin_amdgcn_mfma_f32_16x16x32_f16(al, cur.bh1, acc[af][1], 0, 0, 0);
    }
    cur = nxt;
  }

  // epilogue: bias + LDS transpose + packed-f16 pair-planar store
  float bias[2];
  #pragma unroll
  for (int bt = 0; bt < 2; ++bt) bias[bt] = bref[wn * 32 + bt * 16 + l15];
  float* sb = (float*)smem;
  int fx = t & 63, pl_a = t >> 6;  // pl_a in 0..7
  #pragma unroll 1
  for (int c = 0; c < 4; ++c) {
    __syncthreads();
    if (wn == c) {
      #pragma unroll
      for (int bt = 0; bt < 2; ++bt)
        #pragma unroll
        for (int af = 0; af < 4; ++af)
          #pragma unroll
          for (int reg = 0; reg < 4; ++reg) {
            int px = r * 64 + af * 16 + g * 4 + reg;  // C/D: row=(l>>4)*4+reg, col=l&15
            sb[px * 33 + bt * 16 + l15] = acc[af][bt][reg] + bias[bt];
          }
    }
    __syncthreads();
    // 512 threads store 128 px x 16 pairs: thread handles pairs pl_a and pl_a+8 at px0=2*fx
    int px0 = 2 * fx;
    int rr = fx >> 5;
    int wl = px0 & 63;
    #pragma unroll
    for (int e2 = 0; e2 < 2; ++e2) {
      int p = pl_a + e2 * 8;
      int pair = c * 16 + p;
      uint* gb = offh + ((size_t)(pair * 4 + b) * IMG_N) + (h0 + rr) * WW + w0 + wl;
      __half2 pa = __floats2half2_rn(sb[px0 * 33 + 2 * p], sb[px0 * 33 + 2 * p + 1]);
      __half2 pb = __floats2half2_rn(sb[(px0 + 1) * 33 + 2 * p], sb[(px0 + 1) * 33 + 2 * p + 1]);
      uint2 v = {__builtin_bit_cast(uint, pa), __builtin_bit_cast(uint, pb)};
      *(uint2*)gb = v;
    }
  }
}

// Bilinear tap from LDS f16 image (validated arithmetic, op-for-op).
static __device__ __forceinline__ float tap_img(const __half* img, float ix, float iy) {
  float x0f = floorf(ix), y0f = floorf(iy);
  float fxw = ix - x0f, fyw = iy - y0f;
  int x0 = (int)x0f, y0 = (int)y0f;
  int x1 = x0 + 1, y1 = y0 + 1;
  bool xi0 = (unsigned)x0 < 192u, xi1 = (unsigned)x1 < 192u;
  bool yi0 = (unsigned)y0 < 192u, yi1 = (unsigned)y1 < 192u;
  int xc0 = min(max(x0, 0), 191), xc1 = min(max(x1, 0), 191);
  int yc0 = min(max(y0, 0), 191), yc1 = min(max(y1, 0), 191);
  float v00 = (yi0 && xi0) ? __half2float(img[yc0 * ISTR + xc0]) : 0.0f;
  float v01 = (yi0 && xi1) ? __half2float(img[yc0 * ISTR + xc1]) : 0.0f;
  float v10 = (yi1 && xi0) ? __half2float(img[yc1 * ISTR + xc0]) : 0.0f;
  float v11 = (yi1 && xi1) ? __half2float(img[yc1 * ISTR + xc1]) : 0.0f;
  return v00 * (1.0f - fyw) * (1.0f - fxw) + v01 * (1.0f - fyw) * fxw
       + v10 * fyw * (1.0f - fxw) + v11 * fyw * fxw;
}

// Fused plane-pair processor (R18, validated). Offsets now packed half2 (one uint).
template <int MODE>
__device__ __forceinline__ void plane_pair(
    int m, int c2, int b2, int q, int wv, int lane,
    const float* wk, const float* cx, const float* cy,
    const __half* img, const uint* __restrict__ ob,
    float* pbA, float* pbB,
    const float* __restrict__ x, const float* __restrict__ bws,
    float* __restrict__ out) {
  int p_base = wv * 576 + lane;
  #pragma unroll
  for (int k = 0; k < 9; ++k) {
    int p_rel = p_base + k * 64;
    int phys = p_rel + p_rel / 144;   // swizzle: stride-145 reads, conflict-free
    if (MODE == 2) {
      pbA[phys] = wk[k] * tap_img(img, cx[k], cy[k]);
    } else {
      uint u = ob[p_rel];             // coalesced: 64 consecutive uints per (wv,k)
      float2 o = __half22float2(__builtin_bit_cast(__half2, u));
      float ixN = o.x * 96.0f + cx[k];
      float iyN = o.y * 96.0f + cy[k];
      pbA[phys] = wk[k] * tap_img(img, ixN, iyN);
      float oxS = 2.0f - o.x, oyS = 2.0f - o.y;
      float ixS = oxS * 96.0f + cx[k];
      float iyS = oyS * 96.0f + cy[k];
      float prodS = 0.0f;
      bool inS = (ixS > -1.0f) && (ixS < 192.0f) && (iyS > -1.0f) && (iyS < 192.0f);
      if (__any(inS))                 // sym taps ~99.8% OOB -> wave skip
        prodS = wk[k] * tap_img(img, ixS, iyS);
      pbB[phys] = prodS;
    }
  }
  __syncthreads();  // products visible; caller barriers before pbuf reuse
  // regroup: output (c=wv, w_hi=lane) sums products at s = 144*w_hi + 9*c .. +8
  int c = wv, w_hi = lane;
  int pbase = 145 * w_hi + 9 * c;     // phys of s=144*w_hi+9c; stride 145 -> conflict-free
  float sumA = 0.0f, sumB = 0.0f;
  #pragma unroll
  for (int j = 0; j < 9; ++j) {
    sumA += pbA[pbase + j];
    if (MODE != 2) sumB += pbB[pbase + j];
  }
  int ke2A = (MODE == 2) ? 4 : m;
  {
    int plane_idx = (c2 * 9 + ke2A) * 4 + b2;
    int t16b = plane_idx * 256 + q * 64;
    int w0 = t16b % 192;
    int hb = t16b / 192;
    int h = hb % 192;
    int b = hb / 192;
    size_t addr = ((size_t)(b * 16 + c) * 192 + h) * 192 + w0 + w_hi;
    out[addr] = sumA + bws[c] + x[addr];
  }
  if (MODE != 2) {
    int plane_idx = (c2 * 9 + m + 5) * 4 + b2;
    int t16b = plane_idx * 256 + q * 64;
    int w0 = t16b % 192;
    int hb = t16b / 192;
    int h = hb % 192;
    int b = hb / 192;
    size_t addr = ((size_t)(b * 16 + c) * 192 + h) * 192 + w0 + w_hi;
    out[addr] = sumB + bws[c] + x[addr];
  }
}

// Grid 256: block = (imgid, quarter q).
// LDS: img 74496 | pbufA 37120 | pbufB 37120 = 148736 B.
__global__ __launch_bounds__(1024) void sample_kernel(
    const float* __restrict__ x, const uint* __restrict__ offh,
    const float* __restrict__ Wws, const float* __restrict__ bws,
    float* __restrict__ out) {
  extern __shared__ char smem[];
  __half* img = (__half*)smem;                    // 74496 B
  float* pbufA = (float*)(smem + 74496);          // 37120 B (9280 floats)
  float* pbufB = (float*)(smem + 111616);         // 37120 B
  int ib = blockIdx.x, tid = threadIdx.x;
  int imgid = ib >> 2, q = ib & 3;
  int b2 = imgid & 3, c2 = imgid >> 2;
  int lane = tid & 63, wv = tid >> 6;
  // per-k constants: tap weights + folded base coords (plane-invariant)
  float wk[9], cx[9], cy[9];
  {
    int pb0 = q * 9216 + wv * 576 + lane;
    int h2b = q * 48 + wv * 3;
    #pragma unroll
    for (int k = 0; k < 9; ++k) {
      int p = pb0 + k * 64;
      int ke = p % 9;
      int c = (p / 9) % 16;
      wk[k] = Wws[c * 9 + ke];
      int h2 = h2b + k / 3;
      int w2 = (k % 3) * 64 + lane;
      cx[k] = (float)h2 * (1.0f / 191.0f) * 96.0f + 95.5f;
      cy[k] = (float)w2 * (1.0f / 191.0f) * 96.0f + 95.5f;
    }
  }
  // stage image f32 -> f16, row stride 194 halves (validated)
  const float4* xs = (const float4*)(x + (size_t)(b2 * CC + c2) * IMG_N);
  #pragma unroll
  for (int j = 0; j < 9; ++j) {
    int i4 = j * 1024 + tid;
    float4 v = xs[i4];
    int y = i4 / 48, x0 = (i4 % 48) * 4;
    __half2* ip = (__half2*)(img + y * ISTR + x0);
    ip[0] = __floats2half2_rn(v.x, v.y);
    ip[1] = __floats2half2_rn(v.z, v.w);
  }
  __syncthreads();
  #pragma unroll 1
  for (int m = 0; m < 4; ++m) {
    if (m) __syncthreads();  // previous regroup readers done before pbuf overwrite
    const uint* ob = offh + (size_t)((c2 * 4 + m) * 4 + b2) * IMG_N + q * 9216;
    plane_pair<0>(m, c2, b2, q, wv, lane, wk, cx, cy, img, ob, pbufA, pbufB, x, bws, out);
  }
  __syncthreads();
  plane_pair<2>(0, c2, b2, q, wv, lane, wk, cx, cy, img, (const uint*)nullptr,
                pbufA, pbufB, x, bws, out);
}

extern "C" void kernel_launch(void* const* d_in, const int* in_sizes, int n_in,
                              void* d_out, int out_size, void* d_ws, size_t ws_size,
                              hipStream_t stream) {
  (void)in_sizes; (void)n_in; (void)out_size; (void)ws_size;
  const float* x    = (const float*)d_in[0];
  const float* Wref = (const float*)d_in[1];
  const float* bref = (const float*)d_in[2];
  const float* Wws  = (const float*)d_in[3];
  const float* bws  = (const float*)d_in[4];
  float* out = (float*)d_out;
  uint* Wpack = (uint*)d_ws;                           // 73728 B
  uint* offh = (uint*)((char*)d_ws + 73728);           // 37748736 B (packed half2)

  hipFuncSetAttribute(reinterpret_cast<const void*>(sample_kernel),
                      hipFuncAttributeMaxDynamicSharedMemorySize, 148736);
  prepack_w_kernel<<<9, 256, 0, stream>>>(Wref, Wpack);
  conv_kernel<<<1152, 512, 0, stream>>>(x, Wpack, bref, offh);
  sample_kernel<<<256, 1024, 148736, stream>>>(x, offh, Wws, bws, out);
}

// Round 20
// 67.328 us; speedup vs baseline: 1.6969x; 1.1043x over previous
//
#include <hip/hip_runtime.h>
#include <hip/hip_fp16.h>

// Seesaw_Conv: 3x3 conv (16->128) offsets -> scrambled bilinear sampling -> 9-tap weighted sum + residual
// B=4, C=16, H=W=192, K=3, KE=9, M=4
// ws layout: [0,73728): Wpack (f16 hi/lo B-fragments); [73728,+37748736): offh uint[64][4][192][192]
//   (packed half2: lo=ox, hi=oy).
// Conv: MFMA implicit GEMM, 512-thr block = 2 rows x 64 w x 128 co (R17, validated).
// Sampler V4: zero-BORDER LDS image (pixel (y,x) at img[(y+1)*196+x+2], y,x in [-1,192])
// -> clamp-to-border replaces per-corner masking (saves ~12 VALU/tap); 2-level lerp.

#define HH 192
#define WW 192
#define CC 16
#define CO 128
#define IMG_N (HH * WW)
#define ISTR 196  // bordered img row stride in halves (98 dwords)
#define XSTR 10   // dwords per (row,col) cell in conv packed x-tile

typedef _Float16 f16x8 __attribute__((ext_vector_type(8)));
typedef float f32x4 __attribute__((ext_vector_type(4)));
typedef uint u32x4 __attribute__((ext_vector_type(4)));

static __device__ __forceinline__ f16x8 ld_frag_global(const uint* p) {
  u32x4 v = *(const u32x4*)p;
  return __builtin_bit_cast(f16x8, v);
}

// Prepack W into MFMA B-fragment order, f16 hi+lo. (validated)
__global__ __launch_bounds__(256) void prepack_w_kernel(
    const float* __restrict__ Wref, uint* __restrict__ Wpack) {
  int e = blockIdx.x * 256 + threadIdx.x;
  if (e >= 2304) return;
  int s, btg, l;
  if (e < 2048) { s = e >> 9; int rem = e & 511; btg = rem >> 6; l = rem & 63; }
  else { s = 4; int rem = e - 2048; btg = rem >> 5; l = rem & 31; }
  int g = l >> 4;
  int tap = s * 2 + (g >> 1);
  int co = btg * 16 + (l & 15);
  int cin0 = (g & 1) * 8;
  int kh = (tap * 11) >> 5;
  int kw = tap - 3 * kh;
  uint hd[4], ld[4];
  #pragma unroll
  for (int j = 0; j < 4; ++j) {
    uint hh[2], ll[2];
    #pragma unroll
    for (int q = 0; q < 2; ++q) {
      int i = 2 * j + q;
      float v = Wref[((co * CC + cin0 + i) * 3 + kh) * 3 + kw];
      __half h = __float2half(v);
      __half lo = __float2half(v - __half2float(h));
      hh[q] = __half_as_ushort(h);
      ll[q] = __half_as_ushort(lo);
    }
    hd[j] = hh[0] | (hh[1] << 16);
    ld[j] = ll[0] | (ll[1] << 16);
  }
  uint base = (e < 2048) ? (uint)e * 8u : 16384u + (uint)(btg * 32 + l) * 8u;
  #pragma unroll
  for (int j = 0; j < 4; ++j) { Wpack[base + j] = hd[j]; Wpack[base + 4 + j] = ld[j]; }
}

struct WF { f16x8 bh0, bl0, bh1, bl1; };

static __device__ __forceinline__ WF load_w(const uint* __restrict__ Wpack,
                                            int s, int btg0, int l) {
  WF f;
  u32x4 z4 = {0, 0, 0, 0};
  f.bh0 = __builtin_bit_cast(f16x8, z4);
  f.bl0 = f.bh0; f.bh1 = f.bh0; f.bl1 = f.bh0;
  if (s < 4) {
    const uint* bp0 = Wpack + (size_t)((s * 8 + btg0) * 64 + l) * 8;
    f.bh0 = ld_frag_global(bp0);
    f.bl0 = ld_frag_global(bp0 + 4);
    const uint* bp1 = Wpack + (size_t)((s * 8 + btg0 + 1) * 64 + l) * 8;
    f.bh1 = ld_frag_global(bp1);
    f.bl1 = ld_frag_global(bp1 + 4);
  } else if (l < 32) {
    const uint* bp0 = Wpack + 16384 + (size_t)(btg0 * 32 + l) * 8;
    f.bh0 = ld_frag_global(bp0);
    f.bl0 = ld_frag_global(bp0 + 4);
    const uint* bp1 = Wpack + 16384 + (size_t)((btg0 + 1) * 32 + l) * 8;
    f.bh1 = ld_frag_global(bp1);
    f.bl1 = ld_frag_global(bp1 + 4);
  }
  return f;
}

// MFMA conv (R17 structure, byte-identical to R19). Grid 1152, 512 thr.
__global__ __launch_bounds__(512, 2) void conv_kernel(
    const float* __restrict__ x, const uint* __restrict__ Wpack,
    const float* __restrict__ bref, uint* __restrict__ offh) {
  __shared__ uint smem[2 * 2640];  // XH | XL (21120 B); epilogue reuse: float sb[128*33]
  uint* XH = smem;
  uint* XL = smem + 2640;
  int bid = blockIdx.x;
  int wt_ = bid % 3;
  int hp = (bid / 3) % 96;
  int b = bid / 288;              // grid 1152 -> b in 0..3
  int w0 = wt_ * 64, h0 = hp * 2;
  int t = threadIdx.x;
  int l = t & 63, wv = t >> 6;
  int r = wv & 1, wn = wv >> 1;
  int g = l >> 4, l15 = l & 15;
  int btg0 = wn * 2;

  WF cur = load_w(Wpack, 0, btg0, l);  // overlaps x staging

  for (int idx = t; idx < 2112; idx += 512) {
    int cp = idx / 264;
    int rem = idx - cp * 264;
    int row = rem / 66;
    int col = rem - row * 66;
    int gh = h0 + row - 1, gw = w0 + col - 1;
    float v0 = 0.0f, v1 = 0.0f;
    if ((unsigned)gh < 192u && (unsigned)gw < 192u) {
      const float* gp = x + ((size_t)(b * CC + 2 * cp) * HH + gh) * WW + gw;
      v0 = gp[0];
      v1 = gp[IMG_N];
    }
    __half ha = __float2half(v0), hb = __float2half(v1);
    __half la = __float2half(v0 - __half2float(ha));
    __half lb = __float2half(v1 - __half2float(hb));
    int a = (row * 66 + col) * XSTR + cp;
    XH[a] = (uint)__half_as_ushort(ha) | ((uint)__half_as_ushort(hb) << 16);
    XL[a] = (uint)__half_as_ushort(la) | ((uint)__half_as_ushort(lb) << 16);
  }

  int base0 = (r * 66 + l15) * XSTR + (g & 1) * 4;
  int tapl = g >> 1;
  f32x4 acc[4][2];
  #pragma unroll
  for (int af = 0; af < 4; ++af)
    #pragma unroll
    for (int bt = 0; bt < 2; ++bt) acc[af][bt] = (f32x4){0.f, 0.f, 0.f, 0.f};

  __syncthreads();

  #pragma unroll 1
  for (int s = 0; s < 5; ++s) {
    WF nxt = cur;
    if (s < 4) nxt = load_w(Wpack, s + 1, btg0, l);  // issue early; waits land next iter
    int tap = s * 2 + tapl;
    if (tap > 8) tap = 8;
    int kh = (tap * 11) >> 5;
    int kw = tap - 3 * kh;
    int delta = (kh * 66 + kw) * XSTR;
    #pragma unroll
    for (int af = 0; af < 4; ++af) {
      int ap = base0 + af * (16 * XSTR) + delta;
      uint2 h01 = *(const uint2*)&XH[ap];
      uint2 h23 = *(const uint2*)&XH[ap + 2];
      uint2 l01 = *(const uint2*)&XL[ap];
      uint2 l23 = *(const uint2*)&XL[ap + 2];
      u32x4 th = {h01.x, h01.y, h23.x, h23.y};
      u32x4 tl = {l01.x, l01.y, l23.x, l23.y};
      f16x8 ah = __builtin_bit_cast(f16x8, th);
      f16x8 al = __builtin_bit_cast(f16x8, tl);
      acc[af][0] = __builtin_amdgcn_mfma_f32_16x16x32_f16(ah, cur.bh0, acc[af][0], 0, 0, 0);
      acc[af][0] = __builtin_amdgcn_mfma_f32_16x16x32_f16(ah, cur.bl0, acc[af][0], 0, 0, 0);
      acc[af][0] = __builtin_amdgcn_mfma_f32_16x16x32_f16(al, cur.bh0, acc[af][0], 0, 0, 0);
      acc[af][1] = __builtin_amdgcn_mfma_f32_16x16x32_f16(ah, cur.bh1, acc[af][1], 0, 0, 0);
      acc[af][1] = __builtin_amdgcn_mfma_f32_16x16x32_f16(ah, cur.bl1, acc[af][1], 0, 0, 0);
      acc[af][1] = __builtin_amdgcn_mfma_f32_16x16x32_f16(al, cur.bh1, acc[af][1], 0, 0, 0);
    }
    cur = nxt;
  }

  // epilogue: bias + LDS transpose + packed-f16 pair-planar store
  float bias[2];
  #pragma unroll
  for (int bt = 0; bt < 2; ++bt) bias[bt] = bref[wn * 32 + bt * 16 + l15];
  float* sb = (float*)smem;
  int fx = t & 63, pl_a = t >> 6;  // pl_a in 0..7
  #pragma unroll 1
  for (int c = 0; c < 4; ++c) {
    __syncthreads();
    if (wn == c) {
      #pragma unroll
      for (int bt = 0; bt < 2; ++bt)
        #pragma unroll
        for (int af = 0; af < 4; ++af)
          #pragma unroll
          for (int reg = 0; reg < 4; ++reg) {
            int px = r * 64 + af * 16 + g * 4 + reg;  // C/D: row=(l>>4)*4+reg, col=l&15
            sb[px * 33 + bt * 16 + l15] = acc[af][bt][reg] + bias[bt];
          }
    }
    __syncthreads();
    int px0 = 2 * fx;
    int rr = fx >> 5;
    int wl = px0 & 63;
    #pragma unroll
    for (int e2 = 0; e2 < 2; ++e2) {
      int p = pl_a + e2 * 8;
      int pair = c * 16 + p;
      uint* gb = offh + ((size_t)(pair * 4 + b) * IMG_N) + (h0 + rr) * WW + w0 + wl;
      __half2 pa = __floats2half2_rn(sb[px0 * 33 + 2 * p], sb[px0 * 33 + 2 * p + 1]);
      __half2 pb = __floats2half2_rn(sb[(px0 + 1) * 33 + 2 * p], sb[(px0 + 1) * 33 + 2 * p + 1]);
      uint2 v = {__builtin_bit_cast(uint, pa), __builtin_bit_cast(uint, pb)};
      *(uint2*)gb = v;
    }
  }
}

// Bordered bilinear tap: pixel (y,x) at img[(y+1)*ISTR + x + 2]; border cells are zero,
// so clamp-to-[-1,192] reproduces zero-padding per corner with no masks.
static __device__ __forceinline__ float tap_img(const __half* img, float ix, float iy) {
  float x0f = floorf(ix), y0f = floorf(iy);
  float fx = ix - x0f, fy = iy - y0f;
  int x0 = (int)x0f, y0 = (int)y0f;
  int xc0 = min(max(x0, -1), 192);
  int xc1 = min(max(x0 + 1, -1), 192);
  int yc0 = min(max(y0, -1), 192);
  int yc1 = min(max(y0 + 1, -1), 192);
  const __half* r0 = img + (yc0 + 1) * ISTR + 2;
  const __half* r1 = img + (yc1 + 1) * ISTR + 2;
  float v00 = __half2float(r0[xc0]);
  float v01 = __half2float(r0[xc1]);
  float v10 = __half2float(r1[xc0]);
  float v11 = __half2float(r1[xc1]);
  float top = v00 + fx * (v01 - v00);
  float bot = v10 + fx * (v11 - v10);
  return top + fy * (bot - top);
}

// Fused plane-pair processor (R18 structure, validated).
template <int MODE>
__device__ __forceinline__ void plane_pair(
    int m, int c2, int b2, int q, int wv, int lane,
    const float* wk, const float* cx, const float* cy,
    const __half* img, const uint* __restrict__ ob,
    float* pbA, float* pbB,
    const float* __restrict__ x, const float* __restrict__ bws,
    float* __restrict__ out) {
  int p_base = wv * 576 + lane;
  #pragma unroll
  for (int k = 0; k < 9; ++k) {
    int p_rel = p_base + k * 64;
    int phys = p_rel + p_rel / 144;   // swizzle: stride-145 reads, conflict-free
    if (MODE == 2) {
      pbA[phys] = wk[k] * tap_img(img, cx[k], cy[k]);
    } else {
      uint u = ob[p_rel];             // coalesced: 64 consecutive uints per (wv,k)
      float2 o = __half22float2(__builtin_bit_cast(__half2, u));
      float ixN = o.x * 96.0f + cx[k];
      float iyN = o.y * 96.0f + cy[k];
      pbA[phys] = wk[k] * tap_img(img, ixN, iyN);
      float oxS = 2.0f - o.x, oyS = 2.0f - o.y;
      float ixS = oxS * 96.0f + cx[k];
      float iyS = oyS * 96.0f + cy[k];
      float prodS = 0.0f;
      bool inS = (ixS > -1.0f) && (ixS < 192.0f) && (iyS > -1.0f) && (iyS < 192.0f);
      if (__any(inS))                 // sym taps ~99.8% OOB -> wave skip
        prodS = wk[k] * tap_img(img, ixS, iyS);
      pbB[phys] = prodS;
    }
  }
  __syncthreads();  // products visible; caller barriers before pbuf reuse
  int c = wv, w_hi = lane;
  int pbase = 145 * w_hi + 9 * c;     // stride 145 across lanes -> conflict-free
  float sumA = 0.0f, sumB = 0.0f;
  #pragma unroll
  for (int j = 0; j < 9; ++j) {
    sumA += pbA[pbase + j];
    if (MODE != 2) sumB += pbB[pbase + j];
  }
  int ke2A = (MODE == 2) ? 4 : m;
  {
    int plane_idx = (c2 * 9 + ke2A) * 4 + b2;
    int t16b = plane_idx * 256 + q * 64;
    int w0 = t16b % 192;
    int hb = t16b / 192;
    int h = hb % 192;
    int b = hb / 192;
    size_t addr = ((size_t)(b * 16 + c) * 192 + h) * 192 + w0 + w_hi;
    out[addr] = sumA + bws[c] + x[addr];
  }
  if (MODE != 2) {
    int plane_idx = (c2 * 9 + m + 5) * 4 + b2;
    int t16b = plane_idx * 256 + q * 64;
    int w0 = t16b % 192;
    int hb = t16b / 192;
    int h = hb % 192;
    int b = hb / 192;
    size_t addr = ((size_t)(b * 16 + c) * 192 + h) * 192 + w0 + w_hi;
    out[addr] = sumB + bws[c] + x[addr];
  }
}

// Grid 256: block = (imgid, quarter q).
// LDS: bordered img 76048 | pbufA 37120 | pbufB 37120 = 150288 B.
__global__ __launch_bounds__(1024) void sample_kernel(
    const float* __restrict__ x, const uint* __restrict__ offh,
    const float* __restrict__ Wws, const float* __restrict__ bws,
    float* __restrict__ out) {
  extern __shared__ char smem[];
  __half* img = (__half*)smem;                    // 194 rows x 196 halves = 76048 B
  float* pbufA = (float*)(smem + 76048);          // 37120 B (9280 floats)
  float* pbufB = (float*)(smem + 113168);         // 37120 B
  int ib = blockIdx.x, tid = threadIdx.x;
  int imgid = ib >> 2, q = ib & 3;
  int b2 = imgid & 3, c2 = imgid >> 2;
  int lane = tid & 63, wv = tid >> 6;
  // per-k constants: tap weights + folded base coords (plane-invariant)
  float wk[9], cx[9], cy[9];
  {
    int pb0 = q * 9216 + wv * 576 + lane;
    int h2b = q * 48 + wv * 3;
    #pragma unroll
    for (int k = 0; k < 9; ++k) {
      int p = pb0 + k * 64;
      int ke = p % 9;
      int c = (p / 9) % 16;
      wk[k] = Wws[c * 9 + ke];
      int h2 = h2b + k / 3;
      int w2 = (k % 3) * 64 + lane;
      cx[k] = (float)h2 * (1.0f / 191.0f) * 96.0f + 95.5f;
      cy[k] = (float)w2 * (1.0f / 191.0f) * 96.0f + 95.5f;
    }
  }
  // zero the border cells (rows 0,193 fully; cols 1,194 of rows 1..192)
  ushort* imgu = (ushort*)img;
  for (int i = tid; i < 2 * ISTR; i += 1024) {
    int rr = i / ISTR, cc = i % ISTR;
    imgu[(rr ? 193 : 0) * ISTR + cc] = 0;
  }
  if (tid < 384) {
    int rr = (tid >> 1) + 1;
    int cc = (tid & 1) ? 194 : 1;
    imgu[rr * ISTR + cc] = 0;
  }
  // stage image f32 -> f16 into bordered layout (x+2 keeps half2 stores 4B-aligned)
  const float4* xs = (const float4*)(x + (size_t)(b2 * CC + c2) * IMG_N);
  #pragma unroll
  for (int j = 0; j < 9; ++j) {
    int i4 = j * 1024 + tid;
    float4 v = xs[i4];
    int y = i4 / 48, x0 = (i4 % 48) * 4;
    __half2* ip = (__half2*)(img + (y + 1) * ISTR + x0 + 2);
    ip[0] = __floats2half2_rn(v.x, v.y);
    ip[1] = __floats2half2_rn(v.z, v.w);
  }
  __syncthreads();
  #pragma unroll 1
  for (int m = 0; m < 4; ++m) {
    if (m) __syncthreads();  // previous regroup readers done before pbuf overwrite
    const uint* ob = offh + (size_t)((c2 * 4 + m) * 4 + b2) * IMG_N + q * 9216;
    plane_pair<0>(m, c2, b2, q, wv, lane, wk, cx, cy, img, ob, pbufA, pbufB, x, bws, out);
  }
  __syncthreads();
  plane_pair<2>(0, c2, b2, q, wv, lane, wk, cx, cy, img, (const uint*)nullptr,
                pbufA, pbufB, x, bws, out);
}

extern "C" void kernel_launch(void* const* d_in, const int* in_sizes, int n_in,
                              void* d_out, int out_size, void* d_ws, size_t ws_size,
                              hipStream_t stream) {
  (void)in_sizes; (void)n_in; (void)out_size; (void)ws_size;
  const float* x    = (const float*)d_in[0];
  const float* Wref = (const float*)d_in[1];
  const float* bref = (const float*)d_in[2];
  const float* Wws  = (const float*)d_in[3];
  const float* bws  = (const float*)d_in[4];
  float* out = (float*)d_out;
  uint* Wpack = (uint*)d_ws;                           // 73728 B
  uint* offh = (uint*)((char*)d_ws + 73728);           // 37748736 B (packed half2)

  hipFuncSetAttribute(reinterpret_cast<const void*>(sample_kernel),
                      hipFuncAttributeMaxDynamicSharedMemorySize, 150288);
  prepack_w_kernel<<<9, 256, 0, stream>>>(Wref, Wpack);
  conv_kernel<<<1152, 512, 0, stream>>>(x, Wpack, bref, offh);
  sample_kernel<<<256, 1024, 150288, stream>>>(x, offh, Wws, bws, out);
}

// Round 21
// 63.570 us; speedup vs baseline: 1.7972x; 1.0591x over previous
//
#include <hip/hip_runtime.h>
#include <hip/hip_fp16.h>

// Seesaw_Conv: 3x3 conv (16->128) offsets -> scrambled bilinear sampling -> 9-tap weighted sum + residual
// B=4, C=16, H=W=192, K=3, KE=9, M=4
// ws layout: [0,73728): Wpack (f16 hi/lo B-fragments); [73728,+37748736): offh uint[64][4][192][192]
//   (packed half2: lo=ox, hi=oy).
// Conv: MFMA implicit GEMM, 512-thr block = 2 rows x 64 w x 128 co (R17/R19, validated).
// Sampler V5: zero-border LDS image (R20) + PACKED-half2 product buffers -> TWO m-planes
// per gather pass (pbufP1=(m,m+5), pbufP2=(m+1,m+6)); passes 5->3, barriers 9->5.

#define HH 192
#define WW 192
#define CC 16
#define CO 128
#define IMG_N (HH * WW)
#define ISTR 196  // bordered img row stride in halves (98 dwords)
#define XSTR 10   // dwords per (row,col) cell in conv packed x-tile

typedef _Float16 f16x8 __attribute__((ext_vector_type(8)));
typedef float f32x4 __attribute__((ext_vector_type(4)));
typedef uint u32x4 __attribute__((ext_vector_type(4)));

static __device__ __forceinline__ f16x8 ld_frag_global(const uint* p) {
  u32x4 v = *(const u32x4*)p;
  return __builtin_bit_cast(f16x8, v);
}

// Prepack W into MFMA B-fragment order, f16 hi+lo. (validated)
__global__ __launch_bounds__(256) void prepack_w_kernel(
    const float* __restrict__ Wref, uint* __restrict__ Wpack) {
  int e = blockIdx.x * 256 + threadIdx.x;
  if (e >= 2304) return;
  int s, btg, l;
  if (e < 2048) { s = e >> 9; int rem = e & 511; btg = rem >> 6; l = rem & 63; }
  else { s = 4; int rem = e - 2048; btg = rem >> 5; l = rem & 31; }
  int g = l >> 4;
  int tap = s * 2 + (g >> 1);
  int co = btg * 16 + (l & 15);
  int cin0 = (g & 1) * 8;
  int kh = (tap * 11) >> 5;
  int kw = tap - 3 * kh;
  uint hd[4], ld[4];
  #pragma unroll
  for (int j = 0; j < 4; ++j) {
    uint hh[2], ll[2];
    #pragma unroll
    for (int q = 0; q < 2; ++q) {
      int i = 2 * j + q;
      float v = Wref[((co * CC + cin0 + i) * 3 + kh) * 3 + kw];
      __half h = __float2half(v);
      __half lo = __float2half(v - __half2float(h));
      hh[q] = __half_as_ushort(h);
      ll[q] = __half_as_ushort(lo);
    }
    hd[j] = hh[0] | (hh[1] << 16);
    ld[j] = ll[0] | (ll[1] << 16);
  }
  uint base = (e < 2048) ? (uint)e * 8u : 16384u + (uint)(btg * 32 + l) * 8u;
  #pragma unroll
  for (int j = 0; j < 4; ++j) { Wpack[base + j] = hd[j]; Wpack[base + 4 + j] = ld[j]; }
}

struct WF { f16x8 bh0, bl0, bh1, bl1; };

static __device__ __forceinline__ WF load_w(const uint* __restrict__ Wpack,
                                            int s, int btg0, int l) {
  WF f;
  u32x4 z4 = {0, 0, 0, 0};
  f.bh0 = __builtin_bit_cast(f16x8, z4);
  f.bl0 = f.bh0; f.bh1 = f.bh0; f.bl1 = f.bh0;
  if (s < 4) {
    const uint* bp0 = Wpack + (size_t)((s * 8 + btg0) * 64 + l) * 8;
    f.bh0 = ld_frag_global(bp0);
    f.bl0 = ld_frag_global(bp0 + 4);
    const uint* bp1 = Wpack + (size_t)((s * 8 + btg0 + 1) * 64 + l) * 8;
    f.bh1 = ld_frag_global(bp1);
    f.bl1 = ld_frag_global(bp1 + 4);
  } else if (l < 32) {
    const uint* bp0 = Wpack + 16384 + (size_t)(btg0 * 32 + l) * 8;
    f.bh0 = ld_frag_global(bp0);
    f.bl0 = ld_frag_global(bp0 + 4);
    const uint* bp1 = Wpack + 16384 + (size_t)((btg0 + 1) * 32 + l) * 8;
    f.bh1 = ld_frag_global(bp1);
    f.bl1 = ld_frag_global(bp1 + 4);
  }
  return f;
}

// MFMA conv (R17 structure, byte-identical to R19/R20). Grid 1152, 512 thr.
__global__ __launch_bounds__(512, 2) void conv_kernel(
    const float* __restrict__ x, const uint* __restrict__ Wpack,
    const float* __restrict__ bref, uint* __restrict__ offh) {
  __shared__ uint smem[2 * 2640];  // XH | XL (21120 B); epilogue reuse: float sb[128*33]
  uint* XH = smem;
  uint* XL = smem + 2640;
  int bid = blockIdx.x;
  int wt_ = bid % 3;
  int hp = (bid / 3) % 96;
  int b = bid / 288;              // grid 1152 -> b in 0..3
  int w0 = wt_ * 64, h0 = hp * 2;
  int t = threadIdx.x;
  int l = t & 63, wv = t >> 6;
  int r = wv & 1, wn = wv >> 1;
  int g = l >> 4, l15 = l & 15;
  int btg0 = wn * 2;

  WF cur = load_w(Wpack, 0, btg0, l);  // overlaps x staging

  for (int idx = t; idx < 2112; idx += 512) {
    int cp = idx / 264;
    int rem = idx - cp * 264;
    int row = rem / 66;
    int col = rem - row * 66;
    int gh = h0 + row - 1, gw = w0 + col - 1;
    float v0 = 0.0f, v1 = 0.0f;
    if ((unsigned)gh < 192u && (unsigned)gw < 192u) {
      const float* gp = x + ((size_t)(b * CC + 2 * cp) * HH + gh) * WW + gw;
      v0 = gp[0];
      v1 = gp[IMG_N];
    }
    __half ha = __float2half(v0), hb = __float2half(v1);
    __half la = __float2half(v0 - __half2float(ha));
    __half lb = __float2half(v1 - __half2float(hb));
    int a = (row * 66 + col) * XSTR + cp;
    XH[a] = (uint)__half_as_ushort(ha) | ((uint)__half_as_ushort(hb) << 16);
    XL[a] = (uint)__half_as_ushort(la) | ((uint)__half_as_ushort(lb) << 16);
  }

  int base0 = (r * 66 + l15) * XSTR + (g & 1) * 4;
  int tapl = g >> 1;
  f32x4 acc[4][2];
  #pragma unroll
  for (int af = 0; af < 4; ++af)
    #pragma unroll
    for (int bt = 0; bt < 2; ++bt) acc[af][bt] = (f32x4){0.f, 0.f, 0.f, 0.f};

  __syncthreads();

  #pragma unroll 1
  for (int s = 0; s < 5; ++s) {
    WF nxt = cur;
    if (s < 4) nxt = load_w(Wpack, s + 1, btg0, l);  // issue early; waits land next iter
    int tap = s * 2 + tapl;
    if (tap > 8) tap = 8;
    int kh = (tap * 11) >> 5;
    int kw = tap - 3 * kh;
    int delta = (kh * 66 + kw) * XSTR;
    #pragma unroll
    for (int af = 0; af < 4; ++af) {
      int ap = base0 + af * (16 * XSTR) + delta;
      uint2 h01 = *(const uint2*)&XH[ap];
      uint2 h23 = *(const uint2*)&XH[ap + 2];
      uint2 l01 = *(const uint2*)&XL[ap];
      uint2 l23 = *(const uint2*)&XL[ap + 2];
      u32x4 th = {h01.x, h01.y, h23.x, h23.y};
      u32x4 tl = {l01.x, l01.y, l23.x, l23.y};
      f16x8 ah = __builtin_bit_cast(f16x8, th);
      f16x8 al = __builtin_bit_cast(f16x8, tl);
      acc[af][0] = __builtin_amdgcn_mfma_f32_16x16x32_f16(ah, cur.bh0, acc[af][0], 0, 0, 0);
      acc[af][0] = __builtin_amdgcn_mfma_f32_16x16x32_f16(ah, cur.bl0, acc[af][0], 0, 0, 0);
      acc[af][0] = __builtin_amdgcn_mfma_f32_16x16x32_f16(al, cur.bh0, acc[af][0], 0, 0, 0);
      acc[af][1] = __builtin_amdgcn_mfma_f32_16x16x32_f16(ah, cur.bh1, acc[af][1], 0, 0, 0);
      acc[af][1] = __builtin_amdgcn_mfma_f32_16x16x32_f16(ah, cur.bl1, acc[af][1], 0, 0, 0);
      acc[af][1] = __builtin_amdgcn_mfma_f32_16x16x32_f16(al, cur.bh1, acc[af][1], 0, 0, 0);
    }
    cur = nxt;
  }

  // epilogue: bias + LDS transpose + packed-f16 pair-planar store
  float bias[2];
  #pragma unroll
  for (int bt = 0; bt < 2; ++bt) bias[bt] = bref[wn * 32 + bt * 16 + l15];
  float* sb = (float*)smem;
  int fx = t & 63, pl_a = t >> 6;  // pl_a in 0..7
  #pragma unroll 1
  for (int c = 0; c < 4; ++c) {
    __syncthreads();
    if (wn == c) {
      #pragma unroll
      for (int bt = 0; bt < 2; ++bt)
        #pragma unroll
        for (int af = 0; af < 4; ++af)
          #pragma unroll
          for (int reg = 0; reg < 4; ++reg) {
            int px = r * 64 + af * 16 + g * 4 + reg;  // C/D: row=(l>>4)*4+reg, col=l&15
            sb[px * 33 + bt * 16 + l15] = acc[af][bt][reg] + bias[bt];
          }
    }
    __syncthreads();
    int px0 = 2 * fx;
    int rr = fx >> 5;
    int wl = px0 & 63;
    #pragma unroll
    for (int e2 = 0; e2 < 2; ++e2) {
      int p = pl_a + e2 * 8;
      int pair = c * 16 + p;
      uint* gb = offh + ((size_t)(pair * 4 + b) * IMG_N) + (h0 + rr) * WW + w0 + wl;
      __half2 pa = __floats2half2_rn(sb[px0 * 33 + 2 * p], sb[px0 * 33 + 2 * p + 1]);
      __half2 pb = __floats2half2_rn(sb[(px0 + 1) * 33 + 2 * p], sb[(px0 + 1) * 33 + 2 * p + 1]);
      uint2 v = {__builtin_bit_cast(uint, pa), __builtin_bit_cast(uint, pb)};
      *(uint2*)gb = v;
    }
  }
}

// Bordered bilinear tap: pixel (y,x) at img[(y+1)*ISTR + x + 2]; border cells are zero,
// so clamp-to-[-1,192] reproduces zero-padding per corner with no masks. (R20, validated)
static __device__ __forceinline__ float tap_img(const __half* img, float ix, float iy) {
  float x0f = floorf(ix), y0f = floorf(iy);
  float fx = ix - x0f, fy = iy - y0f;
  int x0 = (int)x0f, y0 = (int)y0f;
  int xc0 = min(max(x0, -1), 192);
  int xc1 = min(max(x0 + 1, -1), 192);
  int yc0 = min(max(y0, -1), 192);
  int yc1 = min(max(y0 + 1, -1), 192);
  const __half* r0 = img + (yc0 + 1) * ISTR + 2;
  const __half* r1 = img + (yc1 + 1) * ISTR + 2;
  float v00 = __half2float(r0[xc0]);
  float v01 = __half2float(r0[xc1]);
  float v10 = __half2float(r1[xc0]);
  float v11 = __half2float(r1[xc1]);
  float top = v00 + fx * (v01 - v00);
  float bot = v10 + fx * (v11 - v10);
  return top + fy * (bot - top);
}

// Compute one (normal, sym) product pair for plane m from one packed offset.
static __device__ __forceinline__ __half2 pair_prods(
    uint u, float wkk, float cxk, float cyk, const __half* img) {
  float2 o = __half22float2(__builtin_bit_cast(__half2, u));
  float ixN = o.x * 96.0f + cxk;
  float iyN = o.y * 96.0f + cyk;
  float prodN = wkk * tap_img(img, ixN, iyN);
  float oxS = 2.0f - o.x, oyS = 2.0f - o.y;
  float ixS = oxS * 96.0f + cxk;
  float iyS = oyS * 96.0f + cyk;
  float prodS = 0.0f;
  bool inS = (ixS > -1.0f) && (ixS < 192.0f) && (iyS > -1.0f) && (iyS < 192.0f);
  if (__any(inS))                   // sym taps ~99.8% OOB -> wave skip
    prodS = wkk * tap_img(img, ixS, iyS);
  return __floats2half2_rn(prodN, prodS);
}

static __device__ __forceinline__ void write_out(
    int ke2, int c2, int b2, int q, int c, int w_hi, float sum,
    const float* __restrict__ x, const float* __restrict__ bws,
    float* __restrict__ out) {
  int plane_idx = (c2 * 9 + ke2) * 4 + b2;
  int t16b = plane_idx * 256 + q * 64;
  int w0 = t16b % 192;
  int hb = t16b / 192;
  int h = hb % 192;
  int b = hb / 192;
  size_t addr = ((size_t)(b * 16 + c) * 192 + h) * 192 + w0 + w_hi;
  out[addr] = sum + bws[c] + x[addr];
}

// Fused plane-QUAD processor. MODE 0: gather planes m,m+1 (and syms m+5,m+6) in one pass;
// packed half2 products (N,S) into pbufP1 (plane m) and pbufP2 (plane m+1).
// MODE 2: center plane only -> pbufP1 (lo half).
template <int MODE>
__device__ __forceinline__ void plane_quad(
    int m, int c2, int b2, int q, int wv, int lane,
    const float* wk, const float* cx, const float* cy,
    const __half* img, const uint* __restrict__ ob,
    uint* pbP1, uint* pbP2,
    const float* __restrict__ x, const float* __restrict__ bws,
    float* __restrict__ out) {
  int p_base = wv * 576 + lane;
  #pragma unroll
  for (int k = 0; k < 9; ++k) {
    int p_rel = p_base + k * 64;
    int phys = p_rel + p_rel / 144;   // swizzle: stride-145 reads, conflict-free
    if (MODE == 2) {
      float prod = wk[k] * tap_img(img, cx[k], cy[k]);
      pbP1[phys] = __builtin_bit_cast(uint, __floats2half2_rn(prod, 0.0f));
    } else {
      uint u1 = ob[p_rel];                     // plane m (coalesced)
      uint u2 = ob[p_rel + 4 * IMG_N];         // plane m+1 (pair index +1)
      pbP1[phys] = __builtin_bit_cast(uint, pair_prods(u1, wk[k], cx[k], cy[k], img));
      pbP2[phys] = __builtin_bit_cast(uint, pair_prods(u2, wk[k], cx[k], cy[k], img));
    }
  }
  __syncthreads();  // products visible; caller barriers before pbuf reuse
  // regroup: output (c=wv, w_hi=lane); phys base = 145*w_hi + 9*c; stride 145 conflict-free
  int c = wv, w_hi = lane;
  int pbase = 145 * w_hi + 9 * c;
  float sA = 0.0f, sB = 0.0f, sC = 0.0f, sD = 0.0f;
  #pragma unroll
  for (int j = 0; j < 9; ++j) {
    float2 f1 = __half22float2(__builtin_bit_cast(__half2, pbP1[pbase + j]));
    sA += f1.x;
    if (MODE != 2) {
      sB += f1.y;
      float2 f2 = __half22float2(__builtin_bit_cast(__half2, pbP2[pbase + j]));
      sC += f2.x;
      sD += f2.y;
    }
  }
  if (MODE == 2) {
    write_out(4, c2, b2, q, c, w_hi, sA, x, bws, out);
  } else {
    write_out(m, c2, b2, q, c, w_hi, sA, x, bws, out);
    write_out(m + 5, c2, b2, q, c, w_hi, sB, x, bws, out);
    write_out(m + 1, c2, b2, q, c, w_hi, sC, x, bws, out);
    write_out(m + 6, c2, b2, q, c, w_hi, sD, x, bws, out);
  }
}

// Grid 256: block = (imgid, quarter q).
// LDS: bordered img 76048 | pbufP1 37120 | pbufP2 37120 = 150288 B. 3 passes, 5 barriers.
__global__ __launch_bounds__(1024) void sample_kernel(
    const float* __restrict__ x, const uint* __restrict__ offh,
    const float* __restrict__ Wws, const float* __restrict__ bws,
    float* __restrict__ out) {
  extern __shared__ char smem[];
  __half* img = (__half*)smem;                    // 194 rows x 196 halves = 76048 B
  uint* pbP1 = (uint*)(smem + 76048);             // 37120 B (9280 uints, packed half2)
  uint* pbP2 = (uint*)(smem + 113168);            // 37120 B
  int ib = blockIdx.x, tid = threadIdx.x;
  int imgid = ib >> 2, q = ib & 3;
  int b2 = imgid & 3, c2 = imgid >> 2;
  int lane = tid & 63, wv = tid >> 6;
  // per-k constants: tap weights + folded base coords (plane-invariant)
  float wk[9], cx[9], cy[9];
  {
    int pb0 = q * 9216 + wv * 576 + lane;
    int h2b = q * 48 + wv * 3;
    #pragma unroll
    for (int k = 0; k < 9; ++k) {
      int p = pb0 + k * 64;
      int ke = p % 9;
      int c = (p / 9) % 16;
      wk[k] = Wws[c * 9 + ke];
      int h2 = h2b + k / 3;
      int w2 = (k % 3) * 64 + lane;
      cx[k] = (float)h2 * (1.0f / 191.0f) * 96.0f + 95.5f;
      cy[k] = (float)w2 * (1.0f / 191.0f) * 96.0f + 95.5f;
    }
  }
  // zero the border cells (rows 0,193 fully; cols 1,194 of rows 1..192)
  ushort* imgu = (ushort*)img;
  for (int i = tid; i < 2 * ISTR; i += 1024) {
    int rr = i / ISTR, cc = i % ISTR;
    imgu[(rr ? 193 : 0) * ISTR + cc] = 0;
  }
  if (tid < 384) {
    int rr = (tid >> 1) + 1;
    int cc = (tid & 1) ? 194 : 1;
    imgu[rr * ISTR + cc] = 0;
  }
  // stage image f32 -> f16 into bordered layout
  const float4* xs = (const float4*)(x + (size_t)(b2 * CC + c2) * IMG_N);
  #pragma unroll
  for (int j = 0; j < 9; ++j) {
    int i4 = j * 1024 + tid;
    float4 v = xs[i4];
    int y = i4 / 48, x0 = (i4 % 48) * 4;
    __half2* ip = (__half2*)(img + (y + 1) * ISTR + x0 + 2);
    ip[0] = __floats2half2_rn(v.x, v.y);
    ip[1] = __floats2half2_rn(v.z, v.w);
  }
  __syncthreads();
  #pragma unroll 1
  for (int mp = 0; mp < 2; ++mp) {
    if (mp) __syncthreads();  // previous regroup readers done before pbuf overwrite
    int m = mp * 2;
    const uint* ob = offh + (size_t)((c2 * 4 + m) * 4 + b2) * IMG_N + q * 9216;
    plane_quad<0>(m, c2, b2, q, wv, lane, wk, cx, cy, img, ob, pbP1, pbP2, x, bws, out);
  }
  __syncthreads();
  plane_quad<2>(0, c2, b2, q, wv, lane, wk, cx, cy, img, (const uint*)nullptr,
                pbP1, pbP2, x, bws, out);
}

extern "C" void kernel_launch(void* const* d_in, const int* in_sizes, int n_in,
                              void* d_out, int out_size, void* d_ws, size_t ws_size,
                              hipStream_t stream) {
  (void)in_sizes; (void)n_in; (void)out_size; (void)ws_size;
  const float* x    = (const float*)d_in[0];
  const float* Wref = (const float*)d_in[1];
  const float* bref = (const float*)d_in[2];
  const float* Wws  = (const float*)d_in[3];
  const float* bws  = (const float*)d_in[4];
  float* out = (float*)d_out;
  uint* Wpack = (uint*)d_ws;                           // 73728 B
  uint* offh = (uint*)((char*)d_ws + 73728);           // 37748736 B (packed half2)

  hipFuncSetAttribute(reinterpret_cast<const void*>(sample_kernel),
                      hipFuncAttributeMaxDynamicSharedMemorySize, 150288);
  prepack_w_kernel<<<9, 256, 0, stream>>>(Wref, Wpack);
  conv_kernel<<<1152, 512, 0, stream>>>(x, Wpack, bref, offh);
  sample_kernel<<<256, 1024, 150288, stream>>>(x, offh, Wws, bws, out);
}